// Round 9
// baseline (1457.491 us; speedup 1.0000x reference)
//
#include <hip/hip_runtime.h>
#include <hip/hip_fp16.h>
#include <math.h>

#define N_NODES  500000
#define N_EDGES  8000000
#define N_GRAPHS 25000
#define SD  119   // 20+27+36+36 concatenated segment-sum dim
#define RD  175
#define H1  96
#define H2  63
#define NT  138
#define GPB 16    // graphs per block in dense kernels

#define B2SHIFT 11
#define B2NODES 2048
#define NBUCK2  245          // ceil(500000/2048)
#define REG     40960        // fixed edge-slot region per bucket (mean 32768, +45 sigma)
#define BIN_CHUNK 4096
#define NB_BIN 1954          // ceil(8e6/4096)
#define NBF 7813             // ceil(500000/64) fused-layer blocks
#define CSR_CAP 1536         // staged csr indices per 64-node block (mean span 1024, sd ~32)

static __device__ __forceinline__ float selu_f(float m){
    const float scale=1.0507009873554805f, alpha=1.6732632423543772f;
    return m > 0.0f ? scale*m : scale*alpha*(__expf(m)-1.0f);
}

// packed fp16 max on raw 32-bit words (v_pk_max_f16, VOP3P, gfx950)
static __device__ __forceinline__ unsigned pkmax(unsigned a, unsigned b){
    unsigned r;
    asm volatile("v_pk_max_f16 %0, %1, %2" : "=v"(r) : "v"(a), "v"(b));
    return r;
}

static __device__ __forceinline__ float2 h2_to_f2(unsigned u){
    union{ unsigned u; __half2 h; } c; c.u = u;
    return __half22float2(c.h);
}

static __device__ __forceinline__ void nt_store_h2(__half2 hv, __half2* p){
    union { __half2 h; unsigned u; } cv; cv.h = hv;
    __builtin_nontemporal_store(cv.u, (unsigned*)p);
}

// single-barrier block scan building block: 64-lane inclusive shfl scan
static __device__ __forceinline__ int wave_incl_scan(int v){
    int lane = threadIdx.x & 63;
    #pragma unroll
    for(int off=1; off<64; off<<=1){
        int u = __shfl_up(v, off, 64);
        if(lane >= off) v += u;
    }
    return v;
}

// ---------------- init: zero S + init bucket cursors to region bases ----------------
__global__ void k_init(int* bcur, float* S){
    int i = blockIdx.x*256 + threadIdx.x;
    if(i < NBUCK2) bcur[i] = i*REG;
    if(i < N_GRAPHS*SD) S[i] = 0.f;
}

// ---------------- binning pass: LDS-staged, bulk-reserved into fixed bucket regions ----------------
// NOTE (round-7 lesson): direct random 4B scatter writes cost ~64B write-allocate
// per edge (~550us). This LDS-staged two-pass build keeps all global writes coalesced.
__global__ __launch_bounds__(256) void k_bin(const int* __restrict__ src, const int* __restrict__ dst,
                                             int* __restrict__ bcur, int* __restrict__ packed){
    __shared__ int   stage[BIN_CHUNK];
    __shared__ unsigned char bkt[BIN_CHUNK];
    __shared__ int lhist[256], lstart[256], lcur[256], gbase[256];
    __shared__ int wsum[4];
    int t = threadIdx.x;
    int base = blockIdx.x*BIN_CHUNK;
    int myb[16], mys[16];
    #pragma unroll
    for(int k=0;k<16;k++){
        int e = base + k*256 + t;
        if(e < N_EDGES){
            int d = __builtin_nontemporal_load(&dst[e]);     // streaming, zero reuse
            int s = __builtin_nontemporal_load(&src[e]);
            myb[k] = d >> B2SHIFT;
            mys[k] = ((d & (B2NODES-1)) << 19) | s;
        } else myb[k] = -1;
    }
    lhist[t]=0; __syncthreads();
    #pragma unroll
    for(int k=0;k<16;k++) if(myb[k]>=0) atomicAdd(&lhist[myb[k]],1);
    __syncthreads();
    int v = lhist[t];
    int incl = wave_incl_scan(v);
    if((t&63)==63) wsum[t>>6] = incl;
    __syncthreads();
    int wbase = 0;
    for(int w=0; w<(t>>6); w++) wbase += wsum[w];
    int exc = wbase + incl - v;
    lstart[t]=exc; lcur[t]=exc;
    if(t < NBUCK2 && v>0) gbase[t] = atomicAdd(&bcur[t], v);
    __syncthreads();
    #pragma unroll
    for(int k=0;k<16;k++){
        if(myb[k]>=0){
            int p = atomicAdd(&lcur[myb[k]],1);
            stage[p]=mys[k]; bkt[p]=(unsigned char)myb[k];
        }
    }
    __syncthreads();
    int total = N_EDGES - base; if(total > BIN_CHUNK) total = BIN_CHUNK;
    for(int i=t; i<total; i+=256){
        int b = bkt[i];
        packed[gbase[b] + (i - lstart[b])] = stage[i];
    }
}

// ---------------- fine scatter per 2048-node bucket: fused hist+scan(row_beg/end)+scatter ----------------
// packed reads stay NORMAL (two passes over the same ~160KB region: second pass L2-hits)
__global__ __launch_bounds__(1024) void k_scatfine(const int* __restrict__ bcur,
                          const int* __restrict__ packed, int* __restrict__ row_beg,
                          int* __restrict__ row_end, int* __restrict__ csr){
    __shared__ int cnt[B2NODES];
    __shared__ int wsum[16];
    int t = threadIdx.x;
    int b = blockIdx.x;
    int nb = b << B2SHIFT;
    cnt[t]=0; cnt[t+1024]=0;
    __syncthreads();
    int ebeg = b*REG, eend = bcur[b];
    for(int e=ebeg+t; e<eend; e+=1024){
        int dl = packed[e] >> 19;
        atomicAdd(&cnt[dl],1);
    }
    __syncthreads();
    int c0 = cnt[2*t], c1 = cnt[2*t+1];
    int s = c0+c1;
    int incl = wave_incl_scan(s);
    if((t&63)==63) wsum[t>>6] = incl;
    __syncthreads();           // separates all cnt reads above from writes below
    int wbase=0;
    for(int w=0; w<(t>>6); w++) wbase += wsum[w];
    int excl = wbase + incl - s;
    int e0 = excl, e1 = excl + c0;
    cnt[2*t]=e0; cnt[2*t+1]=e1;
    int n0 = nb + 2*t, n1 = nb + 2*t + 1;
    if(n0 < N_NODES){ row_beg[n0]=ebeg+e0; row_end[n0]=ebeg+e0+c0; }
    if(n1 < N_NODES){ row_beg[n1]=ebeg+e1; row_end[n1]=ebeg+e1+c1; }
    __syncthreads();
    for(int e=ebeg+t; e<eend; e+=1024){
        int v = packed[e];
        int dl = v >> 19;
        int pos = ebeg + atomicAdd(&cnt[dl],1);
        csr[pos] = v & 0x7FFFF;
    }
}

// ---------------- node transform (layer 1 only) -> fp16 y, 64B rows (32 halfs, zero pad) ----------------
template<int DIN,int DOUT,int PIN,int PH>
__global__ __launch_bounds__(256) void k_transform_h(const float* __restrict__ x, const float* __restrict__ W,
                                                     const float* __restrict__ bias, __half* __restrict__ y){
    __shared__ float swp[PIN*PH];
    __shared__ float sbp[PH];
    int t = threadIdx.x;
    for(int i=t;i<PIN*PH;i+=256){
        int row=i/PH, o=i-row*PH;
        swp[i] = (row<DIN && o<DOUT) ? W[row*DOUT+o] : 0.f;
    }
    if(t<PH) sbp[t] = (t<DOUT) ? bias[t] : 0.f;
    __syncthreads();
    const int TPN = PH/2;
    int gid = blockIdx.x*256 + t;
    if(gid >= N_NODES*TPN) return;
    int n = gid/TPN, op = gid - n*TPN;
    int o0 = 2*op, o1 = o0+1;
    const float4* xr4 = (const float4*)(x + (size_t)n*PIN);
    float acc0 = sbp[o0], acc1 = sbp[o1];
    #pragma unroll
    for(int i4=0;i4<PIN/4;i4++){
        float4 xv = xr4[i4];
        acc0 = fmaf(xv.x, swp[(4*i4+0)*PH+o0], acc0);
        acc1 = fmaf(xv.x, swp[(4*i4+0)*PH+o1], acc1);
        acc0 = fmaf(xv.y, swp[(4*i4+1)*PH+o0], acc0);
        acc1 = fmaf(xv.y, swp[(4*i4+1)*PH+o1], acc1);
        acc0 = fmaf(xv.z, swp[(4*i4+2)*PH+o0], acc0);
        acc1 = fmaf(xv.z, swp[(4*i4+2)*PH+o1], acc1);
        acc0 = fmaf(xv.w, swp[(4*i4+3)*PH+o0], acc0);
        acc1 = fmaf(xv.w, swp[(4*i4+3)*PH+o1], acc1);
    }
    __half2* y2 = (__half2*)y;
    nt_store_h2(__floats2half2_rn(acc0, acc1), &y2[(size_t)n*TPN + op]);
}

// ---------------- gather-max core: 16B lanes from 64B-aligned 64B-stride rows ----------------
template<class IDX>
static __device__ __forceinline__ void gather_max_m(const __half* __restrict__ ymain,
        IDX idx, int beg, int end, unsigned offb, unsigned m[4]){
    const char* __restrict__ yb = (const char*)ymain;
    unsigned m0=m[0], m1=m[1], m2=m[2], m3=m[3];
    int j = beg;
    for(; j+8<=end; j+=8){
        int s0=idx(j+0), s1=idx(j+1), s2=idx(j+2), s3=idx(j+3);
        int s4=idx(j+4), s5=idx(j+5), s6=idx(j+6), s7=idx(j+7);
        uint4 v0 = *(const uint4*)(yb + ((unsigned)s0*64u + offb));
        uint4 v1 = *(const uint4*)(yb + ((unsigned)s1*64u + offb));
        uint4 v2 = *(const uint4*)(yb + ((unsigned)s2*64u + offb));
        uint4 v3 = *(const uint4*)(yb + ((unsigned)s3*64u + offb));
        uint4 v4 = *(const uint4*)(yb + ((unsigned)s4*64u + offb));
        uint4 v5 = *(const uint4*)(yb + ((unsigned)s5*64u + offb));
        uint4 v6 = *(const uint4*)(yb + ((unsigned)s6*64u + offb));
        uint4 v7 = *(const uint4*)(yb + ((unsigned)s7*64u + offb));
        m0=pkmax(m0,v0.x); m1=pkmax(m1,v0.y); m2=pkmax(m2,v0.z); m3=pkmax(m3,v0.w);
        m0=pkmax(m0,v1.x); m1=pkmax(m1,v1.y); m2=pkmax(m2,v1.z); m3=pkmax(m3,v1.w);
        m0=pkmax(m0,v2.x); m1=pkmax(m1,v2.y); m2=pkmax(m2,v2.z); m3=pkmax(m3,v2.w);
        m0=pkmax(m0,v3.x); m1=pkmax(m1,v3.y); m2=pkmax(m2,v3.z); m3=pkmax(m3,v3.w);
        m0=pkmax(m0,v4.x); m1=pkmax(m1,v4.y); m2=pkmax(m2,v4.z); m3=pkmax(m3,v4.w);
        m0=pkmax(m0,v5.x); m1=pkmax(m1,v5.y); m2=pkmax(m2,v5.z); m3=pkmax(m3,v5.w);
        m0=pkmax(m0,v6.x); m1=pkmax(m1,v6.y); m2=pkmax(m2,v6.z); m3=pkmax(m3,v6.w);
        m0=pkmax(m0,v7.x); m1=pkmax(m1,v7.y); m2=pkmax(m2,v7.z); m3=pkmax(m3,v7.w);
    }
    for(; j+4<=end; j+=4){
        int s0=idx(j+0), s1=idx(j+1), s2=idx(j+2), s3=idx(j+3);
        uint4 v0 = *(const uint4*)(yb + ((unsigned)s0*64u + offb));
        uint4 v1 = *(const uint4*)(yb + ((unsigned)s1*64u + offb));
        uint4 v2 = *(const uint4*)(yb + ((unsigned)s2*64u + offb));
        uint4 v3 = *(const uint4*)(yb + ((unsigned)s3*64u + offb));
        m0=pkmax(m0,v0.x); m1=pkmax(m1,v0.y); m2=pkmax(m2,v0.z); m3=pkmax(m3,v0.w);
        m0=pkmax(m0,v1.x); m1=pkmax(m1,v1.y); m2=pkmax(m2,v1.z); m3=pkmax(m3,v1.w);
        m0=pkmax(m0,v2.x); m1=pkmax(m1,v2.y); m2=pkmax(m2,v2.z); m3=pkmax(m3,v2.w);
        m0=pkmax(m0,v3.x); m1=pkmax(m1,v3.y); m2=pkmax(m2,v3.z); m3=pkmax(m3,v3.w);
    }
    for(; j<end; j++){
        int s0 = idx(j);
        uint4 v0 = *(const uint4*)(yb + ((unsigned)s0*64u + offb));
        m0=pkmax(m0,v0.x); m1=pkmax(m1,v0.y); m2=pkmax(m2,v0.z); m3=pkmax(m3,v0.w);
    }
    m[0]=m0; m[1]=m1; m[2]=m2; m[3]=m3;
}

static __device__ __forceinline__ void finish_selu(const unsigned m[4], float o[8]){
    float2 f0=h2_to_f2(m[0]), f1=h2_to_f2(m[1]), f2=h2_to_f2(m[2]), f3=h2_to_f2(m[3]);
    float f[8] = {f0.x,f0.y,f1.x,f1.y,f2.x,f2.y,f3.x,f3.y};
    #pragma unroll
    for(int k=0;k<8;k++){
        float v = f[k];
        if(v < -1e30f) v = 0.0f;    // empty segment (-inf) -> 0
        o[k] = selu_f(v);
    }
}

// ---------------- tail gather: 4 lanes/node, nt csr reads -> 4MB tail array stays L2-resident ----------------
__global__ __launch_bounds__(256) void k_tailgather(const __half* __restrict__ ytail,
        const int* __restrict__ row_beg, const int* __restrict__ row_end,
        const int* __restrict__ csr, float* __restrict__ tf){
    int gid = blockIdx.x*256 + threadIdx.x;
    int n = gid >> 2, l = gid & 3;
    if(n >= N_NODES) return;
    const char* __restrict__ yb = (const char*)ytail;
    int beg = row_beg[n], end = row_end[n];
    unsigned m0=0xFC00FC00u, m1=0xFC00FC00u;
    for(int j=beg+l; j<end; j+=4){
        int s0 = __builtin_nontemporal_load(&csr[j]);
        uint2 v0 = *(const uint2*)(yb + (unsigned)s0*8u);
        m0=pkmax(m0,v0.x); m1=pkmax(m1,v0.y);
    }
    // reduce across the node's 4 lanes (xor 1,2 stays inside aligned 4-groups)
    m0 = pkmax(m0, (unsigned)__shfl_xor((int)m0, 1, 64));
    m1 = pkmax(m1, (unsigned)__shfl_xor((int)m1, 1, 64));
    m0 = pkmax(m0, (unsigned)__shfl_xor((int)m0, 2, 64));
    m1 = pkmax(m1, (unsigned)__shfl_xor((int)m1, 2, 64));
    float2 f0=h2_to_f2(m0), f1=h2_to_f2(m1);
    float v = (l==0)?f0.x:(l==1)?f0.y:(l==2)?f1.x:f1.y;
    if(v < -1e30f) v = 0.f;
    tf[(size_t)n*4 + l] = selu_f(v);   // coalesced 4B/lane
}

// ---------------- fused layer: main gather-max+selu (+tail feats) -> S accum -> next transform ----------------
// 64 nodes/block, FG 16B lanes per node over 64B-aligned rows. TIN: read selu'd tail feats
// from tf (computed by k_tailgather). TNEXT: output has tail rows (dims 32..35).
template<int FG,int TIN,int D_CUR,int SOFF,int D_NEXT,int TNEXT>
__global__ __launch_bounds__(64*FG) void k_fused(
        const __half* __restrict__ ymain, const float* __restrict__ tf,
        const int* __restrict__ row_beg, const int* __restrict__ row_end,
        const int* __restrict__ csr, const int* __restrict__ batch,
        const float* __restrict__ W, const float* __restrict__ bias,
        float* __restrict__ S, __half* __restrict__ youtM, __half* __restrict__ youtT){
    const int NTH = 64*FG;
    const int NF  = TIN ? 36 : 8*FG;
    const int OW  = TNEXT ? 36 : 32;   // output halfs (zero-padded cols beyond D_NEXT)
    __shared__ float feat[64][NF+1];
    __shared__ float sw[D_CUR*OW];
    __shared__ float sb[OW];
    __shared__ int sbatch[64];
    __shared__ int scsr[CSR_CAP];
    int t = threadIdx.x;
    int nl = t / FG, fg = t - nl*FG;
    int base = blockIdx.x*64;
    int n = base + nl;
    for(int i=t;i<D_CUR*OW;i+=NTH){
        int k=i/OW, o2=i-k*OW;
        sw[i] = (o2<D_NEXT) ? W[k*D_NEXT+o2] : 0.f;
    }
    if(t<OW) sb[t] = (t<D_NEXT) ? bias[t] : 0.f;
    if(t<64) sbatch[t] = (base+t<N_NODES) ? batch[base+t] : -1;
    // stage this block's csr index span into LDS (coalesced, nt: zero reuse after staging)
    int last = base + 63; if(last >= N_NODES) last = N_NODES-1;
    int ebeg = row_beg[base];
    int nst = row_end[last] - ebeg; if(nst > CSR_CAP) nst = CSR_CAP;
    for(int i=t;i<nst;i+=NTH) scsr[i] = __builtin_nontemporal_load(&csr[ebeg+i]);
    __syncthreads();
    int slim = ebeg + nst;
    float o[8];
    if(n < N_NODES){
        int beg = row_beg[n], end = row_end[n];
        unsigned m[4] = {0xFC00FC00u,0xFC00FC00u,0xFC00FC00u,0xFC00FC00u};
        unsigned offb = (unsigned)fg*16u;
        if(end <= slim) gather_max_m(ymain, [&](int j){ return scsr[j-ebeg]; }, beg, end, offb, m);
        else            gather_max_m(ymain, [&](int j){ return csr[j]; },       beg, end, offb, m);
        finish_selu(m, o);
    } else {
        for(int k=0;k<8;k++) o[k]=0.f;
    }
    #pragma unroll
    for(int k=0;k<8;k++) feat[nl][8*fg+k] = o[k];
    if(TIN && fg == 0){
        if(n < N_NODES){
            float4 tv = ((const float4*)tf)[n];
            feat[nl][32]=tv.x; feat[nl][33]=tv.y; feat[nl][34]=tv.z; feat[nl][35]=tv.w;
        } else {
            feat[nl][32]=0.f; feat[nl][33]=0.f; feat[nl][34]=0.f; feat[nl][35]=0.f;
        }
    }
    __syncthreads();
    // per-graph run reduction into S (batch sorted)
    if(t < D_CUR){
        float acc=0.f; int gprev = sbatch[0];
        for(int mm=0;mm<64;mm++){
            int g = sbatch[mm];
            if(g<0) break;
            if(g!=gprev){ atomicAdd(&S[(size_t)gprev*SD+SOFF+t], acc); acc=0.f; gprev=g; }
            acc += feat[mm][t];
        }
        if(gprev>=0) atomicAdd(&S[(size_t)gprev*SD+SOFF+t], acc);
    }
    // next-layer transform from LDS; nt stores (streamed out, randomly read next kernel)
    if(n < N_NODES){
        for(int p=fg; p<OW/2; p+=FG){
            int c0=2*p, c1=c0+1;
            float a0=sb[c0], a1=sb[c1];
            #pragma unroll
            for(int k=0;k<D_CUR;k++){
                float fv = feat[nl][k];
                a0 = fmaf(fv, sw[k*OW+c0], a0);
                a1 = fmaf(fv, sw[k*OW+c1], a1);
            }
            __half2 hv = __floats2half2_rn(a0,a1);
            if(!TNEXT || p < 16) nt_store_h2(hv, (__half2*)youtM + (size_t)n*16 + p);
            else                 nt_store_h2(hv, (__half2*)youtT + (size_t)n*2 + (p-16));
        }
    }
}

// ---------------- fused last layer: main gather (+tail feats) -> S accum only ----------------
template<int FG,int TIN,int D_CUR,int SOFF>
__global__ __launch_bounds__(64*FG) void k_fused_last(
        const __half* __restrict__ ymain, const float* __restrict__ tf,
        const int* __restrict__ row_beg, const int* __restrict__ row_end,
        const int* __restrict__ csr, const int* __restrict__ batch,
        float* __restrict__ S){
    const int NTH = 64*FG;
    const int NF  = TIN ? 36 : 8*FG;
    __shared__ float feat[64][NF+1];
    __shared__ int sbatch[64];
    __shared__ int scsr[CSR_CAP];
    int t = threadIdx.x;
    int nl = t / FG, fg = t - nl*FG;
    int base = blockIdx.x*64;
    int n = base + nl;
    if(t<64) sbatch[t] = (base+t<N_NODES) ? batch[base+t] : -1;
    int last = base + 63; if(last >= N_NODES) last = N_NODES-1;
    int ebeg = row_beg[base];
    int nst = row_end[last] - ebeg; if(nst > CSR_CAP) nst = CSR_CAP;
    for(int i=t;i<nst;i+=NTH) scsr[i] = __builtin_nontemporal_load(&csr[ebeg+i]);
    __syncthreads();
    int slim = ebeg + nst;
    float o[8];
    if(n < N_NODES){
        int beg = row_beg[n], end = row_end[n];
        unsigned m[4] = {0xFC00FC00u,0xFC00FC00u,0xFC00FC00u,0xFC00FC00u};
        unsigned offb = (unsigned)fg*16u;
        if(end <= slim) gather_max_m(ymain, [&](int j){ return scsr[j-ebeg]; }, beg, end, offb, m);
        else            gather_max_m(ymain, [&](int j){ return csr[j]; },       beg, end, offb, m);
        finish_selu(m, o);
    } else {
        for(int k=0;k<8;k++) o[k]=0.f;
    }
    #pragma unroll
    for(int k=0;k<8;k++) feat[nl][8*fg+k] = o[k];
    if(TIN && fg == 0){
        if(n < N_NODES){
            float4 tv = ((const float4*)tf)[n];
            feat[nl][32]=tv.x; feat[nl][33]=tv.y; feat[nl][34]=tv.z; feat[nl][35]=tv.w;
        } else {
            feat[nl][32]=0.f; feat[nl][33]=0.f; feat[nl][34]=0.f; feat[nl][35]=0.f;
        }
    }
    __syncthreads();
    if(t < D_CUR){
        float acc=0.f; int gprev = sbatch[0];
        for(int mm=0;mm<64;mm++){
            int g = sbatch[mm];
            if(g<0) break;
            if(g!=gprev){ atomicAdd(&S[(size_t)gprev*SD+SOFF+t], acc); acc=0.f; gprev=g; }
            acc += feat[mm][t];
        }
        if(gprev>=0) atomicAdd(&S[(size_t)gprev*SD+SOFF+t], acc);
    }
}

// ---------------- fused readout + fc1: r = S@Wcat + b (LDS), z1 = [r,mol]@wf + bf, BN stats ----------------
__global__ __launch_bounds__(192) void k_rfc1(const float* __restrict__ S, const float* __restrict__ mol,
    const float* __restrict__ w1,const float* __restrict__ b1,
    const float* __restrict__ w2,const float* __restrict__ b2,
    const float* __restrict__ w3,const float* __restrict__ b3,
    const float* __restrict__ w4,const float* __restrict__ b4,
    const float* __restrict__ wf, const float* __restrict__ bf,
    float* __restrict__ z1, float* __restrict__ ps, float* __restrict__ pq){
    __shared__ float sH[GPB][SD];
    __shared__ float sR[GPB][RD+10];
    int t = threadIdx.x;
    int g0 = blockIdx.x*GPB;
    for(int i=t;i<GPB*SD;i+=192){
        int gl=i/SD, k=i-gl*SD;
        int g=g0+gl;
        sH[gl][k] = (g<N_GRAPHS) ? S[(size_t)g*SD+k] : 0.f;
    }
    for(int i=t;i<GPB*10;i+=192){
        int gl=i/10, k=i-gl*10;
        int g=g0+gl;
        sR[gl][RD+k] = (g<N_GRAPHS) ? mol[(size_t)g*10+k] : 0.f;
    }
    __syncthreads();
    int j = t;
    if(j < RD){
        float acc[GPB];
        float bj = b1[j]+b2[j]+b3[j]+b4[j];
        #pragma unroll
        for(int gl=0;gl<GPB;gl++) acc[gl]=bj;
        for(int k=0;k<20;k++){ float wv=w1[k*RD+j];
            #pragma unroll
            for(int gl=0;gl<GPB;gl++) acc[gl] += sH[gl][k]*wv; }
        for(int k=0;k<27;k++){ float wv=w2[k*RD+j];
            #pragma unroll
            for(int gl=0;gl<GPB;gl++) acc[gl] += sH[gl][20+k]*wv; }
        for(int k=0;k<36;k++){ float wv=w3[k*RD+j];
            #pragma unroll
            for(int gl=0;gl<GPB;gl++) acc[gl] += sH[gl][47+k]*wv; }
        for(int k=0;k<36;k++){ float wv=w4[k*RD+j];
            #pragma unroll
            for(int gl=0;gl<GPB;gl++) acc[gl] += sH[gl][83+k]*wv; }
        #pragma unroll
        for(int gl=0;gl<GPB;gl++) sR[gl][j] = acc[gl];
    }
    __syncthreads();
    if(j < H1){
        float acc[GPB]; float bj=bf[j];
        #pragma unroll
        for(int gl=0;gl<GPB;gl++) acc[gl]=bj;
        for(int k=0;k<RD+10;k++){
            float wv = wf[k*H1+j];
            #pragma unroll
            for(int gl=0;gl<GPB;gl++) acc[gl] += sR[gl][k]*wv;
        }
        int ng = min(GPB, N_GRAPHS-g0);
        float psum=0.f, psq=0.f;
        for(int gl=0;gl<ng;gl++){
            z1[(size_t)(g0+gl)*H1+j]=acc[gl];
            psum+=acc[gl]; psq+=acc[gl]*acc[gl];
        }
        ps[blockIdx.x*H1+j]=psum;
        pq[blockIdx.x*H1+j]=psq;
    }
}

// ---------------- BN finalize: a = g/sqrt(var+eps), c = b - a*mu ----------------
__global__ __launch_bounds__(256) void k_bnfin(const float* __restrict__ ps, const float* __restrict__ pq,
    int nb, int H, const float* __restrict__ gamma, const float* __restrict__ beta,
    float* __restrict__ a, float* __restrict__ c){
    int j = blockIdx.x;
    int t = threadIdx.x;
    float s=0.f, q=0.f;
    for(int i=t;i<nb;i+=256){ s+=ps[(size_t)i*H+j]; q+=pq[(size_t)i*H+j]; }
    __shared__ float sh1[256], sh2[256];
    sh1[t]=s; sh2[t]=q; __syncthreads();
    for(int off=128;off>0;off>>=1){
        if(t<off){ sh1[t]+=sh1[t+off]; sh2[t]+=sh2[t+off]; }
        __syncthreads();
    }
    if(t==0){
        float mean = sh1[0]/(float)N_GRAPHS;
        float var  = sh2[0]/(float)N_GRAPHS - mean*mean;
        float inv  = 1.0f/sqrtf(var + 1e-5f);
        float aj = gamma[j]*inv;
        a[j]=aj; c[j]=beta[j]-aj*mean;
    }
}

// ---------------- fc2: z2 = relu(bn1(z1)) @ w + b, + BN partial stats ----------------
__global__ __launch_bounds__(64) void k_fc2(const float* __restrict__ z1, const float* __restrict__ a1,
    const float* __restrict__ c1, const float* __restrict__ w, const float* __restrict__ b,
    float* __restrict__ z2, float* __restrict__ ps, float* __restrict__ pq){
    __shared__ float sH[GPB][H1];
    int t = threadIdx.x;
    int g0 = blockIdx.x*GPB;
    for(int i=t;i<GPB*H1;i+=64){
        int gl=i/H1, k=i-gl*H1;
        int g=g0+gl;
        float v=0.f;
        if(g<N_GRAPHS){ float z=z1[(size_t)g*H1+k]; v=fmaxf(a1[k]*z+c1[k],0.f); }
        sH[gl][k]=v;
    }
    __syncthreads();
    int j = t;
    if(j < H2){
        float acc[GPB]; float bj=b[j];
        #pragma unroll
        for(int gl=0;gl<GPB;gl++) acc[gl]=bj;
        for(int k=0;k<H1;k++){
            float wv=w[k*H2+j];
            #pragma unroll
            for(int gl=0;gl<GPB;gl++) acc[gl]+=sH[gl][k]*wv;
        }
        int ng=min(GPB,N_GRAPHS-g0);
        float psum=0.f,psq=0.f;
        for(int gl=0;gl<ng;gl++){
            z2[(size_t)(g0+gl)*H2+j]=acc[gl];
            psum+=acc[gl]; psq+=acc[gl]*acc[gl];
        }
        ps[blockIdx.x*H2+j]=psum; pq[blockIdx.x*H2+j]=psq;
    }
}

// ---------------- out: sigmoid(relu(bn2(z2)) @ w + b) ----------------
__global__ __launch_bounds__(192) void k_out(const float* __restrict__ z2, const float* __restrict__ a2,
    const float* __restrict__ c2, const float* __restrict__ w, const float* __restrict__ b,
    float* __restrict__ out){
    __shared__ float sH[GPB][H2];
    int t = threadIdx.x;
    int g0 = blockIdx.x*GPB;
    for(int i=t;i<GPB*H2;i+=192){
        int gl=i/H2, k=i-gl*H2;
        int g=g0+gl;
        float v=0.f;
        if(g<N_GRAPHS){ float z=z2[(size_t)g*H2+k]; v=fmaxf(a2[k]*z+c2[k],0.f); }
        sH[gl][k]=v;
    }
    __syncthreads();
    int j = t;
    if(j < NT){
        float acc[GPB]; float bj=b[j];
        #pragma unroll
        for(int gl=0;gl<GPB;gl++) acc[gl]=bj;
        for(int k=0;k<H2;k++){
            float wv=w[k*NT+j];
            #pragma unroll
            for(int gl=0;gl<GPB;gl++) acc[gl]+=sH[gl][k]*wv;
        }
        int ng=min(GPB,N_GRAPHS-g0);
        for(int gl=0;gl<ng;gl++)
            out[(size_t)(g0+gl)*NT+j] = 1.0f/(1.0f+__expf(-acc[gl]));
    }
}

// ---------------- launcher ----------------
static inline int ceil_div(int a,int b){ return (a+b-1)/b; }

extern "C" void kernel_launch(void* const* d_in, const int* in_sizes, int n_in,
                              void* d_out, int out_size, void* d_ws, size_t ws_size,
                              hipStream_t stream) {
    const float* x     = (const float*)d_in[0];
    const float* mol   = (const float*)d_in[1];
    const int*   ei    = (const int*)  d_in[2];   // [0:E]=src, [E:2E]=dst
    const int*   batch = (const int*)  d_in[3];
    const float* w_g1=(const float*)d_in[4];  const float* b_g1=(const float*)d_in[5];
    const float* w_g2=(const float*)d_in[6];  const float* b_g2=(const float*)d_in[7];
    const float* w_g3=(const float*)d_in[8];  const float* b_g3=(const float*)d_in[9];
    const float* w_g4=(const float*)d_in[10]; const float* b_g4=(const float*)d_in[11];
    const float* w_r1=(const float*)d_in[12]; const float* b_r1=(const float*)d_in[13];
    const float* w_r2=(const float*)d_in[14]; const float* b_r2=(const float*)d_in[15];
    const float* w_r3=(const float*)d_in[16]; const float* b_r3=(const float*)d_in[17];
    const float* w_r4=(const float*)d_in[18]; const float* b_r4=(const float*)d_in[19];
    const float* w_fc1=(const float*)d_in[20]; const float* b_fc1=(const float*)d_in[21];
    const float* bn1_g=(const float*)d_in[22]; const float* bn1_b=(const float*)d_in[23];
    const float* w_fc2=(const float*)d_in[24]; const float* b_fc2=(const float*)d_in[25];
    const float* bn2_g=(const float*)d_in[26]; const float* bn2_b=(const float*)d_in[27];
    const float* w_out=(const float*)d_in[28]; const float* b_out=(const float*)d_in[29];
    float* out = (float*)d_out;

    // workspace carve-up (256B aligned regions)
    char* p = (char*)d_ws;
    auto take=[&](size_t bytes)->char*{ char* q=p; p += (bytes+255)&~(size_t)255; return q; };
    __half* yAm = (__half*)take((size_t)N_NODES*64);   // main rows: 32 halfs, 64B aligned
    __half* yBm = (__half*)take((size_t)N_NODES*64);
    __half* yAt = (__half*)take((size_t)N_NODES*8);    // tail rows: 4 halfs (dims 32..35)
    __half* yBt = (__half*)take((size_t)N_NODES*8);
    float* tf   = (float*)take((size_t)N_NODES*16);    // selu'd tail feats (fp32 x4)
    int* bcur    = (int*)take((size_t)NBUCK2*4);
    int* row_beg = (int*)take((size_t)N_NODES*4);
    int* row_end = (int*)take((size_t)N_NODES*4);
    int* packed  = (int*)take((size_t)NBUCK2*REG*4);
    int* csr     = (int*)take((size_t)NBUCK2*REG*4);
    float* S  = (float*)take((size_t)N_GRAPHS*SD*4);
    float* z1 = (float*)take((size_t)N_GRAPHS*H1*4);
    float* z2 = (float*)take((size_t)N_GRAPHS*H2*4);
    const int NB_G = ceil_div(N_GRAPHS, GPB);   // 1563
    float* p1s=(float*)take((size_t)NB_G*H1*4);
    float* p1q=(float*)take((size_t)NB_G*H1*4);
    float* p2s=(float*)take((size_t)NB_G*H2*4);
    float* p2q=(float*)take((size_t)NB_G*H2*4);
    float* a1=(float*)take(H1*4); float* c1=(float*)take(H1*4);
    float* a2=(float*)take(H2*4); float* c2=(float*)take(H2*4);

    const int* src = ei;
    const int* dst = ei + N_EDGES;

    // ---- CSR build (two-pass, coalesced writes; round-7 proved random 4B scatter = 5x worse) ----
    k_init<<<ceil_div(N_GRAPHS*SD,256),256,0,stream>>>(bcur,S);
    k_bin<<<NB_BIN,256,0,stream>>>(src,dst,bcur,packed);
    k_scatfine<<<NBUCK2,1024,0,stream>>>(bcur,packed,row_beg,row_end,csr);

    // layer 1 transform: x(48 fp32) -> yAm(fp16, 64B rows, D=20 zero-pad)
    k_transform_h<48,20,48,32><<<ceil_div(N_NODES*16,256),256,0,stream>>>(x,w_g1,b_g1,yAm);
    // fused layers: 1-line main gathers; D=36 tail dims via dedicated L2-resident kernel
    k_fused<3,0,20,0, 27,0><<<NBF,192,0,stream>>>(yAm,tf,row_beg,row_end,csr,batch,w_g2,b_g2,S,yBm,yBt);
    k_fused<4,0,27,20,36,1><<<NBF,256,0,stream>>>(yBm,tf,row_beg,row_end,csr,batch,w_g3,b_g3,S,yAm,yAt);
    k_tailgather<<<ceil_div(N_NODES*4,256),256,0,stream>>>(yAt,row_beg,row_end,csr,tf);
    k_fused<4,1,36,47,36,1><<<NBF,256,0,stream>>>(yAm,tf,row_beg,row_end,csr,batch,w_g4,b_g4,S,yBm,yBt);
    k_tailgather<<<ceil_div(N_NODES*4,256),256,0,stream>>>(yBt,row_beg,row_end,csr,tf);
    k_fused_last<4,1,36,83><<<NBF,256,0,stream>>>(yBm,tf,row_beg,row_end,csr,batch,S);

    // dense tail: fused readout+fc1, BN, fc2, BN, out
    k_rfc1<<<NB_G,192,0,stream>>>(S,mol,w_r1,b_r1,w_r2,b_r2,w_r3,b_r3,w_r4,b_r4,w_fc1,b_fc1,z1,p1s,p1q);
    k_bnfin<<<H1,256,0,stream>>>(p1s,p1q,NB_G,H1,bn1_g,bn1_b,a1,c1);
    k_fc2<<<NB_G,64,0,stream>>>(z1,a1,c1,w_fc2,b_fc2,z2,p2s,p2q);
    k_bnfin<<<H2,256,0,stream>>>(p2s,p2q,NB_G,H2,bn2_g,bn2_b,a2,c2);
    k_out<<<NB_G,192,0,stream>>>(z2,a2,c2,w_out,b_out,out);
}

// Round 10
// 1376.723 us; speedup vs baseline: 1.0587x; 1.0587x over previous
//
#include <hip/hip_runtime.h>
#include <hip/hip_fp16.h>
#include <math.h>

#define N_NODES  500000
#define N_EDGES  8000000
#define N_GRAPHS 25000
#define SD  119   // 20+27+36+36 concatenated segment-sum dim
#define RD  175
#define H1  96
#define H2  63
#define NT  138
#define GPB 16    // graphs per block in dense kernels

#define B2SHIFT 11
#define B2NODES 2048
#define NBUCK2  245          // ceil(500000/2048)
#define REG     40960        // fixed edge-slot region per bucket (mean 32768, +45 sigma)
#define BIN_CHUNK 4096
#define NB_BIN 1954          // ceil(8e6/4096)
#define NBF 7813             // ceil(500000/64) fused-layer blocks
#define CSR_CAP 1536         // staged csr indices per 64-node block (mean span 1024, sd ~32)

static __device__ __forceinline__ float selu_f(float m){
    const float scale=1.0507009873554805f, alpha=1.6732632423543772f;
    return m > 0.0f ? scale*m : scale*alpha*(__expf(m)-1.0f);
}

// packed fp16 max on raw 32-bit words (v_pk_max_f16, VOP3P, gfx950)
static __device__ __forceinline__ unsigned pkmax(unsigned a, unsigned b){
    unsigned r;
    asm volatile("v_pk_max_f16 %0, %1, %2" : "=v"(r) : "v"(a), "v"(b));
    return r;
}

static __device__ __forceinline__ float2 h2_to_f2(unsigned u){
    union{ unsigned u; __half2 h; } c; c.u = u;
    return __half22float2(c.h);
}

// single-barrier block scan building block: 64-lane inclusive shfl scan
static __device__ __forceinline__ int wave_incl_scan(int v){
    int lane = threadIdx.x & 63;
    #pragma unroll
    for(int off=1; off<64; off<<=1){
        int u = __shfl_up(v, off, 64);
        if(lane >= off) v += u;
    }
    return v;
}

// ---------------- init: zero S + init bucket cursors to region bases ----------------
__global__ void k_init(int* bcur, float* S){
    int i = blockIdx.x*256 + threadIdx.x;
    if(i < NBUCK2) bcur[i] = i*REG;
    if(i < N_GRAPHS*SD) S[i] = 0.f;
}

// ---------------- binning pass: LDS-staged, bulk-reserved into fixed bucket regions ----------------
// NOTE (round-7 lesson): direct random 4B scatter writes cost ~64B write-allocate
// per edge (~550us). This LDS-staged two-pass build keeps all global writes coalesced.
// NOTE (round-9 lesson): nontemporal stores on fine-grained writes defeat L2 write-
// combining (WRITE_SIZE 42->117MB, +20us/layer) -- no nt hints anywhere.
__global__ __launch_bounds__(256) void k_bin(const int* __restrict__ src, const int* __restrict__ dst,
                                             int* __restrict__ bcur, int* __restrict__ packed){
    __shared__ int   stage[BIN_CHUNK];
    __shared__ unsigned char bkt[BIN_CHUNK];
    __shared__ int lhist[256], lstart[256], lcur[256], gbase[256];
    __shared__ int wsum[4];
    int t = threadIdx.x;
    int base = blockIdx.x*BIN_CHUNK;
    int myb[16], mys[16];
    #pragma unroll
    for(int k=0;k<16;k++){
        int e = base + k*256 + t;
        if(e < N_EDGES){
            int d = dst[e];
            myb[k] = d >> B2SHIFT;
            mys[k] = ((d & (B2NODES-1)) << 19) | src[e];
        } else myb[k] = -1;
    }
    lhist[t]=0; __syncthreads();
    #pragma unroll
    for(int k=0;k<16;k++) if(myb[k]>=0) atomicAdd(&lhist[myb[k]],1);
    __syncthreads();
    int v = lhist[t];
    int incl = wave_incl_scan(v);
    if((t&63)==63) wsum[t>>6] = incl;
    __syncthreads();
    int wbase = 0;
    for(int w=0; w<(t>>6); w++) wbase += wsum[w];
    int exc = wbase + incl - v;
    lstart[t]=exc; lcur[t]=exc;
    if(t < NBUCK2 && v>0) gbase[t] = atomicAdd(&bcur[t], v);
    __syncthreads();
    #pragma unroll
    for(int k=0;k<16;k++){
        if(myb[k]>=0){
            int p = atomicAdd(&lcur[myb[k]],1);
            stage[p]=mys[k]; bkt[p]=(unsigned char)myb[k];
        }
    }
    __syncthreads();
    int total = N_EDGES - base; if(total > BIN_CHUNK) total = BIN_CHUNK;
    for(int i=t; i<total; i+=256){
        int b = bkt[i];
        packed[gbase[b] + (i - lstart[b])] = stage[i];
    }
}

// ---------------- fine scatter per 2048-node bucket: fused hist+scan(row_beg/end)+scatter ----------------
__global__ __launch_bounds__(1024) void k_scatfine(const int* __restrict__ bcur,
                          const int* __restrict__ packed, int* __restrict__ row_beg,
                          int* __restrict__ row_end, int* __restrict__ csr){
    __shared__ int cnt[B2NODES];
    __shared__ int wsum[16];
    int t = threadIdx.x;
    int b = blockIdx.x;
    int nb = b << B2SHIFT;
    cnt[t]=0; cnt[t+1024]=0;
    __syncthreads();
    int ebeg = b*REG, eend = bcur[b];
    for(int e=ebeg+t; e<eend; e+=1024){
        int dl = packed[e] >> 19;
        atomicAdd(&cnt[dl],1);
    }
    __syncthreads();
    int c0 = cnt[2*t], c1 = cnt[2*t+1];
    int s = c0+c1;
    int incl = wave_incl_scan(s);
    if((t&63)==63) wsum[t>>6] = incl;
    __syncthreads();           // separates all cnt reads above from writes below
    int wbase=0;
    for(int w=0; w<(t>>6); w++) wbase += wsum[w];
    int excl = wbase + incl - s;
    int e0 = excl, e1 = excl + c0;
    cnt[2*t]=e0; cnt[2*t+1]=e1;
    int n0 = nb + 2*t, n1 = nb + 2*t + 1;
    if(n0 < N_NODES){ row_beg[n0]=ebeg+e0; row_end[n0]=ebeg+e0+c0; }
    if(n1 < N_NODES){ row_beg[n1]=ebeg+e1; row_end[n1]=ebeg+e1+c1; }
    __syncthreads();
    for(int e=ebeg+t; e<eend; e+=1024){
        int v = packed[e];
        int dl = v >> 19;
        int pos = ebeg + atomicAdd(&cnt[dl],1);
        csr[pos] = v & 0x7FFFF;
    }
}

// ---------------- node transform (layer 1 only) -> fp16 y, 64B rows (32 halfs, zero pad) ----------------
template<int DIN,int DOUT,int PIN,int PH>
__global__ __launch_bounds__(256) void k_transform_h(const float* __restrict__ x, const float* __restrict__ W,
                                                     const float* __restrict__ bias, __half* __restrict__ y){
    __shared__ float swp[PIN*PH];
    __shared__ float sbp[PH];
    int t = threadIdx.x;
    for(int i=t;i<PIN*PH;i+=256){
        int row=i/PH, o=i-row*PH;
        swp[i] = (row<DIN && o<DOUT) ? W[row*DOUT+o] : 0.f;
    }
    if(t<PH) sbp[t] = (t<DOUT) ? bias[t] : 0.f;
    __syncthreads();
    const int TPN = PH/2;
    int gid = blockIdx.x*256 + t;
    if(gid >= N_NODES*TPN) return;
    int n = gid/TPN, op = gid - n*TPN;
    int o0 = 2*op, o1 = o0+1;
    const float4* xr4 = (const float4*)(x + (size_t)n*PIN);
    float acc0 = sbp[o0], acc1 = sbp[o1];
    #pragma unroll
    for(int i4=0;i4<PIN/4;i4++){
        float4 xv = xr4[i4];
        acc0 = fmaf(xv.x, swp[(4*i4+0)*PH+o0], acc0);
        acc1 = fmaf(xv.x, swp[(4*i4+0)*PH+o1], acc1);
        acc0 = fmaf(xv.y, swp[(4*i4+1)*PH+o0], acc0);
        acc1 = fmaf(xv.y, swp[(4*i4+1)*PH+o1], acc1);
        acc0 = fmaf(xv.z, swp[(4*i4+2)*PH+o0], acc0);
        acc1 = fmaf(xv.z, swp[(4*i4+2)*PH+o1], acc1);
        acc0 = fmaf(xv.w, swp[(4*i4+3)*PH+o0], acc0);
        acc1 = fmaf(xv.w, swp[(4*i4+3)*PH+o1], acc1);
    }
    __half2* y2 = (__half2*)y;
    y2[(size_t)n*TPN + op] = __floats2half2_rn(acc0, acc1);
}

// ---------------- gather-max core: 16B lanes from 64B-aligned 64B-stride rows ----------------
template<class IDX>
static __device__ __forceinline__ void gather_max_m(const __half* __restrict__ ymain,
        IDX idx, int beg, int end, unsigned offb, unsigned m[4]){
    const char* __restrict__ yb = (const char*)ymain;
    unsigned m0=m[0], m1=m[1], m2=m[2], m3=m[3];
    int j = beg;
    for(; j+8<=end; j+=8){
        int s0=idx(j+0), s1=idx(j+1), s2=idx(j+2), s3=idx(j+3);
        int s4=idx(j+4), s5=idx(j+5), s6=idx(j+6), s7=idx(j+7);
        uint4 v0 = *(const uint4*)(yb + ((unsigned)s0*64u + offb));
        uint4 v1 = *(const uint4*)(yb + ((unsigned)s1*64u + offb));
        uint4 v2 = *(const uint4*)(yb + ((unsigned)s2*64u + offb));
        uint4 v3 = *(const uint4*)(yb + ((unsigned)s3*64u + offb));
        uint4 v4 = *(const uint4*)(yb + ((unsigned)s4*64u + offb));
        uint4 v5 = *(const uint4*)(yb + ((unsigned)s5*64u + offb));
        uint4 v6 = *(const uint4*)(yb + ((unsigned)s6*64u + offb));
        uint4 v7 = *(const uint4*)(yb + ((unsigned)s7*64u + offb));
        m0=pkmax(m0,v0.x); m1=pkmax(m1,v0.y); m2=pkmax(m2,v0.z); m3=pkmax(m3,v0.w);
        m0=pkmax(m0,v1.x); m1=pkmax(m1,v1.y); m2=pkmax(m2,v1.z); m3=pkmax(m3,v1.w);
        m0=pkmax(m0,v2.x); m1=pkmax(m1,v2.y); m2=pkmax(m2,v2.z); m3=pkmax(m3,v2.w);
        m0=pkmax(m0,v3.x); m1=pkmax(m1,v3.y); m2=pkmax(m2,v3.z); m3=pkmax(m3,v3.w);
        m0=pkmax(m0,v4.x); m1=pkmax(m1,v4.y); m2=pkmax(m2,v4.z); m3=pkmax(m3,v4.w);
        m0=pkmax(m0,v5.x); m1=pkmax(m1,v5.y); m2=pkmax(m2,v5.z); m3=pkmax(m3,v5.w);
        m0=pkmax(m0,v6.x); m1=pkmax(m1,v6.y); m2=pkmax(m2,v6.z); m3=pkmax(m3,v6.w);
        m0=pkmax(m0,v7.x); m1=pkmax(m1,v7.y); m2=pkmax(m2,v7.z); m3=pkmax(m3,v7.w);
    }
    for(; j+4<=end; j+=4){
        int s0=idx(j+0), s1=idx(j+1), s2=idx(j+2), s3=idx(j+3);
        uint4 v0 = *(const uint4*)(yb + ((unsigned)s0*64u + offb));
        uint4 v1 = *(const uint4*)(yb + ((unsigned)s1*64u + offb));
        uint4 v2 = *(const uint4*)(yb + ((unsigned)s2*64u + offb));
        uint4 v3 = *(const uint4*)(yb + ((unsigned)s3*64u + offb));
        m0=pkmax(m0,v0.x); m1=pkmax(m1,v0.y); m2=pkmax(m2,v0.z); m3=pkmax(m3,v0.w);
        m0=pkmax(m0,v1.x); m1=pkmax(m1,v1.y); m2=pkmax(m2,v1.z); m3=pkmax(m3,v1.w);
        m0=pkmax(m0,v2.x); m1=pkmax(m1,v2.y); m2=pkmax(m2,v2.z); m3=pkmax(m3,v2.w);
        m0=pkmax(m0,v3.x); m1=pkmax(m1,v3.y); m2=pkmax(m2,v3.z); m3=pkmax(m3,v3.w);
    }
    for(; j<end; j++){
        int s0 = idx(j);
        uint4 v0 = *(const uint4*)(yb + ((unsigned)s0*64u + offb));
        m0=pkmax(m0,v0.x); m1=pkmax(m1,v0.y); m2=pkmax(m2,v0.z); m3=pkmax(m3,v0.w);
    }
    m[0]=m0; m[1]=m1; m[2]=m2; m[3]=m3;
}

static __device__ __forceinline__ void finish_selu(const unsigned m[4], float o[8]){
    float2 f0=h2_to_f2(m[0]), f1=h2_to_f2(m[1]), f2=h2_to_f2(m[2]), f3=h2_to_f2(m[3]);
    float f[8] = {f0.x,f0.y,f1.x,f1.y,f2.x,f2.y,f3.x,f3.y};
    #pragma unroll
    for(int k=0;k<8;k++){
        float v = f[k];
        if(v < -1e30f) v = 0.0f;    // empty segment (-inf) -> 0
        o[k] = selu_f(v);
    }
}

// ---------------- tail gather: 4 lanes/node over 4MB tail array (own kernel -> L2-resident) ----------------
__global__ __launch_bounds__(256) void k_tailgather(const __half* __restrict__ ytail,
        const int* __restrict__ row_beg, const int* __restrict__ row_end,
        const int* __restrict__ csr, float* __restrict__ tf){
    int gid = blockIdx.x*256 + threadIdx.x;
    int n = gid >> 2, l = gid & 3;
    if(n >= N_NODES) return;
    const char* __restrict__ yb = (const char*)ytail;
    int beg = row_beg[n], end = row_end[n];
    unsigned m0=0xFC00FC00u, m1=0xFC00FC00u;
    for(int j=beg+l; j<end; j+=4){
        int s0 = csr[j];
        uint2 v0 = *(const uint2*)(yb + (unsigned)s0*8u);
        m0=pkmax(m0,v0.x); m1=pkmax(m1,v0.y);
    }
    // reduce across the node's 4 lanes (xor 1,2 stays inside aligned 4-groups)
    m0 = pkmax(m0, (unsigned)__shfl_xor((int)m0, 1, 64));
    m1 = pkmax(m1, (unsigned)__shfl_xor((int)m1, 1, 64));
    m0 = pkmax(m0, (unsigned)__shfl_xor((int)m0, 2, 64));
    m1 = pkmax(m1, (unsigned)__shfl_xor((int)m1, 2, 64));
    float2 f0=h2_to_f2(m0), f1=h2_to_f2(m1);
    float v = (l==0)?f0.x:(l==1)?f0.y:(l==2)?f1.x:f1.y;
    if(v < -1e30f) v = 0.f;
    tf[(size_t)n*4 + l] = selu_f(v);   // coalesced 4B/lane
}

// ---------------- fused layer: main gather-max+selu (+tail feats) -> S accum -> next transform ----------------
// 64 nodes/block, FG 16B lanes per node over 64B-aligned rows. TIN: read selu'd tail feats
// from tf (computed by k_tailgather). TNEXT: output has tail rows (dims 32..35).
template<int FG,int TIN,int D_CUR,int SOFF,int D_NEXT,int TNEXT>
__global__ __launch_bounds__(64*FG) void k_fused(
        const __half* __restrict__ ymain, const float* __restrict__ tf,
        const int* __restrict__ row_beg, const int* __restrict__ row_end,
        const int* __restrict__ csr, const int* __restrict__ batch,
        const float* __restrict__ W, const float* __restrict__ bias,
        float* __restrict__ S, __half* __restrict__ youtM, __half* __restrict__ youtT){
    const int NTH = 64*FG;
    const int NF  = TIN ? 36 : 8*FG;
    const int OW  = TNEXT ? 36 : 32;   // output halfs (zero-padded cols beyond D_NEXT)
    __shared__ float feat[64][NF+1];
    __shared__ float sw[D_CUR*OW];
    __shared__ float sb[OW];
    __shared__ int sbatch[64];
    __shared__ int scsr[CSR_CAP];
    int t = threadIdx.x;
    int nl = t / FG, fg = t - nl*FG;
    int base = blockIdx.x*64;
    int n = base + nl;
    for(int i=t;i<D_CUR*OW;i+=NTH){
        int k=i/OW, o2=i-k*OW;
        sw[i] = (o2<D_NEXT) ? W[k*D_NEXT+o2] : 0.f;
    }
    if(t<OW) sb[t] = (t<D_NEXT) ? bias[t] : 0.f;
    if(t<64) sbatch[t] = (base+t<N_NODES) ? batch[base+t] : -1;
    // stage this block's csr index span into LDS (coalesced)
    int last = base + 63; if(last >= N_NODES) last = N_NODES-1;
    int ebeg = row_beg[base];
    int nst = row_end[last] - ebeg; if(nst > CSR_CAP) nst = CSR_CAP;
    for(int i=t;i<nst;i+=NTH) scsr[i] = csr[ebeg+i];
    __syncthreads();
    int slim = ebeg + nst;
    float o[8];
    if(n < N_NODES){
        int beg = row_beg[n], end = row_end[n];
        unsigned m[4] = {0xFC00FC00u,0xFC00FC00u,0xFC00FC00u,0xFC00FC00u};
        unsigned offb = (unsigned)fg*16u;
        if(end <= slim) gather_max_m(ymain, [&](int j){ return scsr[j-ebeg]; }, beg, end, offb, m);
        else            gather_max_m(ymain, [&](int j){ return csr[j]; },       beg, end, offb, m);
        finish_selu(m, o);
    } else {
        for(int k=0;k<8;k++) o[k]=0.f;
    }
    #pragma unroll
    for(int k=0;k<8;k++) feat[nl][8*fg+k] = o[k];
    if(TIN && fg == 0){
        if(n < N_NODES){
            float4 tv = ((const float4*)tf)[n];
            feat[nl][32]=tv.x; feat[nl][33]=tv.y; feat[nl][34]=tv.z; feat[nl][35]=tv.w;
        } else {
            feat[nl][32]=0.f; feat[nl][33]=0.f; feat[nl][34]=0.f; feat[nl][35]=0.f;
        }
    }
    __syncthreads();
    // per-graph run reduction into S (batch sorted)
    if(t < D_CUR){
        float acc=0.f; int gprev = sbatch[0];
        for(int mm=0;mm<64;mm++){
            int g = sbatch[mm];
            if(g<0) break;
            if(g!=gprev){ atomicAdd(&S[(size_t)gprev*SD+SOFF+t], acc); acc=0.f; gprev=g; }
            acc += feat[mm][t];
        }
        if(gprev>=0) atomicAdd(&S[(size_t)gprev*SD+SOFF+t], acc);
    }
    // next-layer transform from LDS
    if(n < N_NODES){
        for(int p=fg; p<OW/2; p+=FG){
            int c0=2*p, c1=c0+1;
            float a0=sb[c0], a1=sb[c1];
            #pragma unroll
            for(int k=0;k<D_CUR;k++){
                float fv = feat[nl][k];
                a0 = fmaf(fv, sw[k*OW+c0], a0);
                a1 = fmaf(fv, sw[k*OW+c1], a1);
            }
            __half2 hv = __floats2half2_rn(a0,a1);
            if(!TNEXT || p < 16) ((__half2*)youtM)[(size_t)n*16 + p] = hv;
            else                 ((__half2*)youtT)[(size_t)n*2 + (p-16)] = hv;
        }
    }
}

// ---------------- fused last layer: main gather (+tail feats) -> S accum only ----------------
template<int FG,int TIN,int D_CUR,int SOFF>
__global__ __launch_bounds__(64*FG) void k_fused_last(
        const __half* __restrict__ ymain, const float* __restrict__ tf,
        const int* __restrict__ row_beg, const int* __restrict__ row_end,
        const int* __restrict__ csr, const int* __restrict__ batch,
        float* __restrict__ S){
    const int NTH = 64*FG;
    const int NF  = TIN ? 36 : 8*FG;
    __shared__ float feat[64][NF+1];
    __shared__ int sbatch[64];
    __shared__ int scsr[CSR_CAP];
    int t = threadIdx.x;
    int nl = t / FG, fg = t - nl*FG;
    int base = blockIdx.x*64;
    int n = base + nl;
    if(t<64) sbatch[t] = (base+t<N_NODES) ? batch[base+t] : -1;
    int last = base + 63; if(last >= N_NODES) last = N_NODES-1;
    int ebeg = row_beg[base];
    int nst = row_end[last] - ebeg; if(nst > CSR_CAP) nst = CSR_CAP;
    for(int i=t;i<nst;i+=NTH) scsr[i] = csr[ebeg+i];
    __syncthreads();
    int slim = ebeg + nst;
    float o[8];
    if(n < N_NODES){
        int beg = row_beg[n], end = row_end[n];
        unsigned m[4] = {0xFC00FC00u,0xFC00FC00u,0xFC00FC00u,0xFC00FC00u};
        unsigned offb = (unsigned)fg*16u;
        if(end <= slim) gather_max_m(ymain, [&](int j){ return scsr[j-ebeg]; }, beg, end, offb, m);
        else            gather_max_m(ymain, [&](int j){ return csr[j]; },       beg, end, offb, m);
        finish_selu(m, o);
    } else {
        for(int k=0;k<8;k++) o[k]=0.f;
    }
    #pragma unroll
    for(int k=0;k<8;k++) feat[nl][8*fg+k] = o[k];
    if(TIN && fg == 0){
        if(n < N_NODES){
            float4 tv = ((const float4*)tf)[n];
            feat[nl][32]=tv.x; feat[nl][33]=tv.y; feat[nl][34]=tv.z; feat[nl][35]=tv.w;
        } else {
            feat[nl][32]=0.f; feat[nl][33]=0.f; feat[nl][34]=0.f; feat[nl][35]=0.f;
        }
    }
    __syncthreads();
    if(t < D_CUR){
        float acc=0.f; int gprev = sbatch[0];
        for(int mm=0;mm<64;mm++){
            int g = sbatch[mm];
            if(g<0) break;
            if(g!=gprev){ atomicAdd(&S[(size_t)gprev*SD+SOFF+t], acc); acc=0.f; gprev=g; }
            acc += feat[mm][t];
        }
        if(gprev>=0) atomicAdd(&S[(size_t)gprev*SD+SOFF+t], acc);
    }
}

// ---------------- fused readout + fc1: r = S@Wcat + b (LDS), z1 = [r,mol]@wf + bf, BN stats ----------------
__global__ __launch_bounds__(192) void k_rfc1(const float* __restrict__ S, const float* __restrict__ mol,
    const float* __restrict__ w1,const float* __restrict__ b1,
    const float* __restrict__ w2,const float* __restrict__ b2,
    const float* __restrict__ w3,const float* __restrict__ b3,
    const float* __restrict__ w4,const float* __restrict__ b4,
    const float* __restrict__ wf, const float* __restrict__ bf,
    float* __restrict__ z1, float* __restrict__ ps, float* __restrict__ pq){
    __shared__ float sH[GPB][SD];
    __shared__ float sR[GPB][RD+10];
    int t = threadIdx.x;
    int g0 = blockIdx.x*GPB;
    for(int i=t;i<GPB*SD;i+=192){
        int gl=i/SD, k=i-gl*SD;
        int g=g0+gl;
        sH[gl][k] = (g<N_GRAPHS) ? S[(size_t)g*SD+k] : 0.f;
    }
    for(int i=t;i<GPB*10;i+=192){
        int gl=i/10, k=i-gl*10;
        int g=g0+gl;
        sR[gl][RD+k] = (g<N_GRAPHS) ? mol[(size_t)g*10+k] : 0.f;
    }
    __syncthreads();
    int j = t;
    if(j < RD){
        float acc[GPB];
        float bj = b1[j]+b2[j]+b3[j]+b4[j];
        #pragma unroll
        for(int gl=0;gl<GPB;gl++) acc[gl]=bj;
        for(int k=0;k<20;k++){ float wv=w1[k*RD+j];
            #pragma unroll
            for(int gl=0;gl<GPB;gl++) acc[gl] += sH[gl][k]*wv; }
        for(int k=0;k<27;k++){ float wv=w2[k*RD+j];
            #pragma unroll
            for(int gl=0;gl<GPB;gl++) acc[gl] += sH[gl][20+k]*wv; }
        for(int k=0;k<36;k++){ float wv=w3[k*RD+j];
            #pragma unroll
            for(int gl=0;gl<GPB;gl++) acc[gl] += sH[gl][47+k]*wv; }
        for(int k=0;k<36;k++){ float wv=w4[k*RD+j];
            #pragma unroll
            for(int gl=0;gl<GPB;gl++) acc[gl] += sH[gl][83+k]*wv; }
        #pragma unroll
        for(int gl=0;gl<GPB;gl++) sR[gl][j] = acc[gl];
    }
    __syncthreads();
    if(j < H1){
        float acc[GPB]; float bj=bf[j];
        #pragma unroll
        for(int gl=0;gl<GPB;gl++) acc[gl]=bj;
        for(int k=0;k<RD+10;k++){
            float wv = wf[k*H1+j];
            #pragma unroll
            for(int gl=0;gl<GPB;gl++) acc[gl] += sR[gl][k]*wv;
        }
        int ng = min(GPB, N_GRAPHS-g0);
        float psum=0.f, psq=0.f;
        for(int gl=0;gl<ng;gl++){
            z1[(size_t)(g0+gl)*H1+j]=acc[gl];
            psum+=acc[gl]; psq+=acc[gl]*acc[gl];
        }
        ps[blockIdx.x*H1+j]=psum;
        pq[blockIdx.x*H1+j]=psq;
    }
}

// ---------------- BN finalize: a = g/sqrt(var+eps), c = b - a*mu ----------------
__global__ __launch_bounds__(256) void k_bnfin(const float* __restrict__ ps, const float* __restrict__ pq,
    int nb, int H, const float* __restrict__ gamma, const float* __restrict__ beta,
    float* __restrict__ a, float* __restrict__ c){
    int j = blockIdx.x;
    int t = threadIdx.x;
    float s=0.f, q=0.f;
    for(int i=t;i<nb;i+=256){ s+=ps[(size_t)i*H+j]; q+=pq[(size_t)i*H+j]; }
    __shared__ float sh1[256], sh2[256];
    sh1[t]=s; sh2[t]=q; __syncthreads();
    for(int off=128;off>0;off>>=1){
        if(t<off){ sh1[t]+=sh1[t+off]; sh2[t]+=sh2[t+off]; }
        __syncthreads();
    }
    if(t==0){
        float mean = sh1[0]/(float)N_GRAPHS;
        float var  = sh2[0]/(float)N_GRAPHS - mean*mean;
        float inv  = 1.0f/sqrtf(var + 1e-5f);
        float aj = gamma[j]*inv;
        a[j]=aj; c[j]=beta[j]-aj*mean;
    }
}

// ---------------- fc2: z2 = relu(bn1(z1)) @ w + b, + BN partial stats ----------------
__global__ __launch_bounds__(64) void k_fc2(const float* __restrict__ z1, const float* __restrict__ a1,
    const float* __restrict__ c1, const float* __restrict__ w, const float* __restrict__ b,
    float* __restrict__ z2, float* __restrict__ ps, float* __restrict__ pq){
    __shared__ float sH[GPB][H1];
    int t = threadIdx.x;
    int g0 = blockIdx.x*GPB;
    for(int i=t;i<GPB*H1;i+=64){
        int gl=i/H1, k=i-gl*H1;
        int g=g0+gl;
        float v=0.f;
        if(g<N_GRAPHS){ float z=z1[(size_t)g*H1+k]; v=fmaxf(a1[k]*z+c1[k],0.f); }
        sH[gl][k]=v;
    }
    __syncthreads();
    int j = t;
    if(j < H2){
        float acc[GPB]; float bj=b[j];
        #pragma unroll
        for(int gl=0;gl<GPB;gl++) acc[gl]=bj;
        for(int k=0;k<H1;k++){
            float wv=w[k*H2+j];
            #pragma unroll
            for(int gl=0;gl<GPB;gl++) acc[gl]+=sH[gl][k]*wv;
        }
        int ng=min(GPB,N_GRAPHS-g0);
        float psum=0.f,psq=0.f;
        for(int gl=0;gl<ng;gl++){
            z2[(size_t)(g0+gl)*H2+j]=acc[gl];
            psum+=acc[gl]; psq+=acc[gl]*acc[gl];
        }
        ps[blockIdx.x*H2+j]=psum; pq[blockIdx.x*H2+j]=psq;
    }
}

// ---------------- out: sigmoid(relu(bn2(z2)) @ w + b) ----------------
__global__ __launch_bounds__(192) void k_out(const float* __restrict__ z2, const float* __restrict__ a2,
    const float* __restrict__ c2, const float* __restrict__ w, const float* __restrict__ b,
    float* __restrict__ out){
    __shared__ float sH[GPB][H2];
    int t = threadIdx.x;
    int g0 = blockIdx.x*GPB;
    for(int i=t;i<GPB*H2;i+=192){
        int gl=i/H2, k=i-gl*H2;
        int g=g0+gl;
        float v=0.f;
        if(g<N_GRAPHS){ float z=z2[(size_t)g*H2+k]; v=fmaxf(a2[k]*z+c2[k],0.f); }
        sH[gl][k]=v;
    }
    __syncthreads();
    int j = t;
    if(j < NT){
        float acc[GPB]; float bj=b[j];
        #pragma unroll
        for(int gl=0;gl<GPB;gl++) acc[gl]=bj;
        for(int k=0;k<H2;k++){
            float wv=w[k*NT+j];
            #pragma unroll
            for(int gl=0;gl<GPB;gl++) acc[gl]+=sH[gl][k]*wv;
        }
        int ng=min(GPB,N_GRAPHS-g0);
        for(int gl=0;gl<ng;gl++)
            out[(size_t)(g0+gl)*NT+j] = 1.0f/(1.0f+__expf(-acc[gl]));
    }
}

// ---------------- launcher ----------------
static inline int ceil_div(int a,int b){ return (a+b-1)/b; }

extern "C" void kernel_launch(void* const* d_in, const int* in_sizes, int n_in,
                              void* d_out, int out_size, void* d_ws, size_t ws_size,
                              hipStream_t stream) {
    const float* x     = (const float*)d_in[0];
    const float* mol   = (const float*)d_in[1];
    const int*   ei    = (const int*)  d_in[2];   // [0:E]=src, [E:2E]=dst
    const int*   batch = (const int*)  d_in[3];
    const float* w_g1=(const float*)d_in[4];  const float* b_g1=(const float*)d_in[5];
    const float* w_g2=(const float*)d_in[6];  const float* b_g2=(const float*)d_in[7];
    const float* w_g3=(const float*)d_in[8];  const float* b_g3=(const float*)d_in[9];
    const float* w_g4=(const float*)d_in[10]; const float* b_g4=(const float*)d_in[11];
    const float* w_r1=(const float*)d_in[12]; const float* b_r1=(const float*)d_in[13];
    const float* w_r2=(const float*)d_in[14]; const float* b_r2=(const float*)d_in[15];
    const float* w_r3=(const float*)d_in[16]; const float* b_r3=(const float*)d_in[17];
    const float* w_r4=(const float*)d_in[18]; const float* b_r4=(const float*)d_in[19];
    const float* w_fc1=(const float*)d_in[20]; const float* b_fc1=(const float*)d_in[21];
    const float* bn1_g=(const float*)d_in[22]; const float* bn1_b=(const float*)d_in[23];
    const float* w_fc2=(const float*)d_in[24]; const float* b_fc2=(const float*)d_in[25];
    const float* bn2_g=(const float*)d_in[26]; const float* bn2_b=(const float*)d_in[27];
    const float* w_out=(const float*)d_in[28]; const float* b_out=(const float*)d_in[29];
    float* out = (float*)d_out;

    // workspace carve-up (256B aligned regions)
    char* p = (char*)d_ws;
    auto take=[&](size_t bytes)->char*{ char* q=p; p += (bytes+255)&~(size_t)255; return q; };
    __half* yAm = (__half*)take((size_t)N_NODES*64);   // main rows: 32 halfs, 64B aligned
    __half* yBm = (__half*)take((size_t)N_NODES*64);
    __half* yAt = (__half*)take((size_t)N_NODES*8);    // tail rows: 4 halfs (dims 32..35)
    __half* yBt = (__half*)take((size_t)N_NODES*8);
    float* tf   = (float*)take((size_t)N_NODES*16);    // selu'd tail feats (fp32 x4)
    int* bcur    = (int*)take((size_t)NBUCK2*4);
    int* row_beg = (int*)take((size_t)N_NODES*4);
    int* row_end = (int*)take((size_t)N_NODES*4);
    int* packed  = (int*)take((size_t)NBUCK2*REG*4);
    int* csr     = (int*)take((size_t)NBUCK2*REG*4);
    float* S  = (float*)take((size_t)N_GRAPHS*SD*4);
    float* z1 = (float*)take((size_t)N_GRAPHS*H1*4);
    float* z2 = (float*)take((size_t)N_GRAPHS*H2*4);
    const int NB_G = ceil_div(N_GRAPHS, GPB);   // 1563
    float* p1s=(float*)take((size_t)NB_G*H1*4);
    float* p1q=(float*)take((size_t)NB_G*H1*4);
    float* p2s=(float*)take((size_t)NB_G*H2*4);
    float* p2q=(float*)take((size_t)NB_G*H2*4);
    float* a1=(float*)take(H1*4); float* c1=(float*)take(H1*4);
    float* a2=(float*)take(H2*4); float* c2=(float*)take(H2*4);

    const int* src = ei;
    const int* dst = ei + N_EDGES;

    // ---- CSR build (two-pass, coalesced writes; round-7 proved random 4B scatter = 5x worse) ----
    k_init<<<ceil_div(N_GRAPHS*SD,256),256,0,stream>>>(bcur,S);
    k_bin<<<NB_BIN,256,0,stream>>>(src,dst,bcur,packed);
    k_scatfine<<<NBUCK2,1024,0,stream>>>(bcur,packed,row_beg,row_end,csr);

    // layer 1 transform: x(48 fp32) -> yAm(fp16, 64B rows, D=20 zero-pad)
    k_transform_h<48,20,48,32><<<ceil_div(N_NODES*16,256),256,0,stream>>>(x,w_g1,b_g1,yAm);
    // fused layers: 1-line main gathers; D=36 tail dims via dedicated L2-resident kernel
    k_fused<3,0,20,0, 27,0><<<NBF,192,0,stream>>>(yAm,tf,row_beg,row_end,csr,batch,w_g2,b_g2,S,yBm,yBt);
    k_fused<4,0,27,20,36,1><<<NBF,256,0,stream>>>(yBm,tf,row_beg,row_end,csr,batch,w_g3,b_g3,S,yAm,yAt);
    k_tailgather<<<ceil_div(N_NODES*4,256),256,0,stream>>>(yAt,row_beg,row_end,csr,tf);
    k_fused<4,1,36,47,36,1><<<NBF,256,0,stream>>>(yAm,tf,row_beg,row_end,csr,batch,w_g4,b_g4,S,yBm,yBt);
    k_tailgather<<<ceil_div(N_NODES*4,256),256,0,stream>>>(yBt,row_beg,row_end,csr,tf);
    k_fused_last<4,1,36,83><<<NBF,256,0,stream>>>(yBm,tf,row_beg,row_end,csr,batch,S);

    // dense tail: fused readout+fc1, BN, fc2, BN, out
    k_rfc1<<<NB_G,192,0,stream>>>(S,mol,w_r1,b_r1,w_r2,b_r2,w_r3,b_r3,w_r4,b_r4,w_fc1,b_fc1,z1,p1s,p1q);
    k_bnfin<<<H1,256,0,stream>>>(p1s,p1q,NB_G,H1,bn1_g,bn1_b,a1,c1);
    k_fc2<<<NB_G,64,0,stream>>>(z1,a1,c1,w_fc2,b_fc2,z2,p2s,p2q);
    k_bnfin<<<H2,256,0,stream>>>(p2s,p2q,NB_G,H2,bn2_g,bn2_b,a2,c2);
    k_out<<<NB_G,192,0,stream>>>(z2,a2,c2,w_out,b_out,out);
}

// Round 11
// 1361.930 us; speedup vs baseline: 1.0702x; 1.0109x over previous
//
#include <hip/hip_runtime.h>
#include <hip/hip_fp16.h>
#include <math.h>

#define N_NODES  500000
#define N_EDGES  8000000
#define N_GRAPHS 25000
#define SD  119   // 20+27+36+36 concatenated segment-sum dim
#define RD  175
#define H1  96
#define H2  63
#define NT  138
#define GPB 16    // graphs per block in dense kernels

#define B2SHIFT 11
#define B2NODES 2048
#define NBUCK2  245          // ceil(500000/2048)
#define REG     40960        // fixed edge-slot region per bucket (mean 32768, +45 sigma)
#define BIN_CHUNK 4096
#define NB_BIN 1954          // ceil(8e6/4096)
#define NBF 7813             // ceil(500000/64) fused-layer blocks
#define CSR_CAP 1536         // staged csr indices per 64-node block (mean span 1024, sd ~32)

static __device__ __forceinline__ float selu_f(float m){
    const float scale=1.0507009873554805f, alpha=1.6732632423543772f;
    return m > 0.0f ? scale*m : scale*alpha*(__expf(m)-1.0f);
}

// packed fp16 max on raw 32-bit words (v_pk_max_f16, VOP3P, gfx950)
static __device__ __forceinline__ unsigned pkmax(unsigned a, unsigned b){
    unsigned r;
    asm volatile("v_pk_max_f16 %0, %1, %2" : "=v"(r) : "v"(a), "v"(b));
    return r;
}

static __device__ __forceinline__ float2 h2_to_f2(unsigned u){
    union{ unsigned u; __half2 h; } c; c.u = u;
    return __half22float2(c.h);
}

// single-barrier block scan building block: 64-lane inclusive shfl scan
static __device__ __forceinline__ int wave_incl_scan(int v){
    int lane = threadIdx.x & 63;
    #pragma unroll
    for(int off=1; off<64; off<<=1){
        int u = __shfl_up(v, off, 64);
        if(lane >= off) v += u;
    }
    return v;
}

// ---------------- init: zero S + init bucket cursors to region bases ----------------
__global__ void k_init(int* bcur, float* S){
    int i = blockIdx.x*256 + threadIdx.x;
    if(i < NBUCK2) bcur[i] = i*REG;
    if(i < N_GRAPHS*SD) S[i] = 0.f;
}

// ---------------- binning pass: LDS-staged, bulk-reserved into fixed bucket regions ----------------
// NOTE (round-7 lesson): direct random 4B scatter writes cost ~64B write-allocate
// per edge (~550us). This LDS-staged two-pass build keeps all global writes coalesced.
// NOTE (round-9 lesson): nontemporal stores on fine-grained writes defeat L2 write-
// combining -- no nt hints anywhere.
// Round-11: per-wave split histograms/cursors (4x less LDS atomic contention).
__global__ __launch_bounds__(256) void k_bin(const int* __restrict__ src, const int* __restrict__ dst,
                                             int* __restrict__ bcur, int* __restrict__ packed){
    __shared__ int   stage[BIN_CHUNK];
    __shared__ unsigned char bkt[BIN_CHUNK];
    __shared__ int lhist[4][256];     // per-wave histograms
    __shared__ int wcur[4][256];      // per-wave scatter cursors
    __shared__ int lstart[256], gbase[256];
    __shared__ int wsum[4];
    int t = threadIdx.x;
    int w = t >> 6;
    int base = blockIdx.x*BIN_CHUNK;
    int myb[16], mys[16];
    #pragma unroll
    for(int k=0;k<16;k++){
        int e = base + k*256 + t;
        if(e < N_EDGES){
            int d = dst[e];
            myb[k] = d >> B2SHIFT;
            mys[k] = ((d & (B2NODES-1)) << 19) | src[e];
        } else myb[k] = -1;
    }
    for(int i=t;i<1024;i+=256) ((int*)lhist)[i]=0;
    __syncthreads();
    #pragma unroll
    for(int k=0;k<16;k++) if(myb[k]>=0) atomicAdd(&lhist[w][myb[k]],1);
    __syncthreads();
    int h0=lhist[0][t], h1=lhist[1][t], h2=lhist[2][t], h3=lhist[3][t];
    int v = h0+h1+h2+h3;
    int incl = wave_incl_scan(v);
    if((t&63)==63) wsum[t>>6] = incl;
    __syncthreads();
    int wbase = 0;
    for(int ww=0; ww<(t>>6); ww++) wbase += wsum[ww];
    int exc = wbase + incl - v;
    lstart[t]=exc;
    int run = exc;
    wcur[0][t]=run; run+=h0;
    wcur[1][t]=run; run+=h1;
    wcur[2][t]=run; run+=h2;
    wcur[3][t]=run;
    if(t < NBUCK2 && v>0) gbase[t] = atomicAdd(&bcur[t], v);
    __syncthreads();
    #pragma unroll
    for(int k=0;k<16;k++){
        if(myb[k]>=0){
            int p = atomicAdd(&wcur[w][myb[k]],1);
            stage[p]=mys[k]; bkt[p]=(unsigned char)myb[k];
        }
    }
    __syncthreads();
    int total = N_EDGES - base; if(total > BIN_CHUNK) total = BIN_CHUNK;
    for(int i=t; i<total; i+=256){
        int b = bkt[i];
        packed[gbase[b] + (i - lstart[b])] = stage[i];
    }
}

// ---------------- fine scatter per 2048-node bucket: fused hist+scan(row_beg/end)+scatter ----------------
__global__ __launch_bounds__(1024) void k_scatfine(const int* __restrict__ bcur,
                          const int* __restrict__ packed, int* __restrict__ row_beg,
                          int* __restrict__ row_end, int* __restrict__ csr){
    __shared__ int cnt[B2NODES];
    __shared__ int wsum[16];
    int t = threadIdx.x;
    int b = blockIdx.x;
    int nb = b << B2SHIFT;
    cnt[t]=0; cnt[t+1024]=0;
    __syncthreads();
    int ebeg = b*REG, eend = bcur[b];
    for(int e=ebeg+t; e<eend; e+=1024){
        int dl = packed[e] >> 19;
        atomicAdd(&cnt[dl],1);
    }
    __syncthreads();
    int c0 = cnt[2*t], c1 = cnt[2*t+1];
    int s = c0+c1;
    int incl = wave_incl_scan(s);
    if((t&63)==63) wsum[t>>6] = incl;
    __syncthreads();           // separates all cnt reads above from writes below
    int wbase=0;
    for(int w=0; w<(t>>6); w++) wbase += wsum[w];
    int excl = wbase + incl - s;
    int e0 = excl, e1 = excl + c0;
    cnt[2*t]=e0; cnt[2*t+1]=e1;
    int n0 = nb + 2*t, n1 = nb + 2*t + 1;
    if(n0 < N_NODES){ row_beg[n0]=ebeg+e0; row_end[n0]=ebeg+e0+c0; }
    if(n1 < N_NODES){ row_beg[n1]=ebeg+e1; row_end[n1]=ebeg+e1+c1; }
    __syncthreads();
    for(int e=ebeg+t; e<eend; e+=1024){
        int v = packed[e];
        int dl = v >> 19;
        int pos = ebeg + atomicAdd(&cnt[dl],1);
        csr[pos] = v & 0x7FFFF;
    }
}

// ---------------- node transform (layer 1 only) -> fp16 y, 64B rows (32 halfs, zero pad) ----------------
template<int DIN,int DOUT,int PIN,int PH>
__global__ __launch_bounds__(256) void k_transform_h(const float* __restrict__ x, const float* __restrict__ W,
                                                     const float* __restrict__ bias, __half* __restrict__ y){
    __shared__ float swp[PIN*PH];
    __shared__ float sbp[PH];
    int t = threadIdx.x;
    for(int i=t;i<PIN*PH;i+=256){
        int row=i/PH, o=i-row*PH;
        swp[i] = (row<DIN && o<DOUT) ? W[row*DOUT+o] : 0.f;
    }
    if(t<PH) sbp[t] = (t<DOUT) ? bias[t] : 0.f;
    __syncthreads();
    const int TPN = PH/2;
    int gid = blockIdx.x*256 + t;
    if(gid >= N_NODES*TPN) return;
    int n = gid/TPN, op = gid - n*TPN;
    int o0 = 2*op, o1 = o0+1;
    const float4* xr4 = (const float4*)(x + (size_t)n*PIN);
    float acc0 = sbp[o0], acc1 = sbp[o1];
    #pragma unroll
    for(int i4=0;i4<PIN/4;i4++){
        float4 xv = xr4[i4];
        acc0 = fmaf(xv.x, swp[(4*i4+0)*PH+o0], acc0);
        acc1 = fmaf(xv.x, swp[(4*i4+0)*PH+o1], acc1);
        acc0 = fmaf(xv.y, swp[(4*i4+1)*PH+o0], acc0);
        acc1 = fmaf(xv.y, swp[(4*i4+1)*PH+o1], acc1);
        acc0 = fmaf(xv.z, swp[(4*i4+2)*PH+o0], acc0);
        acc1 = fmaf(xv.z, swp[(4*i4+2)*PH+o1], acc1);
        acc0 = fmaf(xv.w, swp[(4*i4+3)*PH+o0], acc0);
        acc1 = fmaf(xv.w, swp[(4*i4+3)*PH+o1], acc1);
    }
    __half2* y2 = (__half2*)y;
    y2[(size_t)n*TPN + op] = __floats2half2_rn(acc0, acc1);
}

// ---------------- gather-max core: 16B lanes from 64B-aligned 64B-stride rows ----------------
template<class IDX>
static __device__ __forceinline__ void gather_max_m(const __half* __restrict__ ymain,
        IDX idx, int beg, int end, unsigned offb, unsigned m[4]){
    const char* __restrict__ yb = (const char*)ymain;
    unsigned m0=m[0], m1=m[1], m2=m[2], m3=m[3];
    int j = beg;
    for(; j+8<=end; j+=8){
        int s0=idx(j+0), s1=idx(j+1), s2=idx(j+2), s3=idx(j+3);
        int s4=idx(j+4), s5=idx(j+5), s6=idx(j+6), s7=idx(j+7);
        uint4 v0 = *(const uint4*)(yb + ((unsigned)s0*64u + offb));
        uint4 v1 = *(const uint4*)(yb + ((unsigned)s1*64u + offb));
        uint4 v2 = *(const uint4*)(yb + ((unsigned)s2*64u + offb));
        uint4 v3 = *(const uint4*)(yb + ((unsigned)s3*64u + offb));
        uint4 v4 = *(const uint4*)(yb + ((unsigned)s4*64u + offb));
        uint4 v5 = *(const uint4*)(yb + ((unsigned)s5*64u + offb));
        uint4 v6 = *(const uint4*)(yb + ((unsigned)s6*64u + offb));
        uint4 v7 = *(const uint4*)(yb + ((unsigned)s7*64u + offb));
        m0=pkmax(m0,v0.x); m1=pkmax(m1,v0.y); m2=pkmax(m2,v0.z); m3=pkmax(m3,v0.w);
        m0=pkmax(m0,v1.x); m1=pkmax(m1,v1.y); m2=pkmax(m2,v1.z); m3=pkmax(m3,v1.w);
        m0=pkmax(m0,v2.x); m1=pkmax(m1,v2.y); m2=pkmax(m2,v2.z); m3=pkmax(m3,v2.w);
        m0=pkmax(m0,v3.x); m1=pkmax(m1,v3.y); m2=pkmax(m2,v3.z); m3=pkmax(m3,v3.w);
        m0=pkmax(m0,v4.x); m1=pkmax(m1,v4.y); m2=pkmax(m2,v4.z); m3=pkmax(m3,v4.w);
        m0=pkmax(m0,v5.x); m1=pkmax(m1,v5.y); m2=pkmax(m2,v5.z); m3=pkmax(m3,v5.w);
        m0=pkmax(m0,v6.x); m1=pkmax(m1,v6.y); m2=pkmax(m2,v6.z); m3=pkmax(m3,v6.w);
        m0=pkmax(m0,v7.x); m1=pkmax(m1,v7.y); m2=pkmax(m2,v7.z); m3=pkmax(m3,v7.w);
    }
    for(; j+4<=end; j+=4){
        int s0=idx(j+0), s1=idx(j+1), s2=idx(j+2), s3=idx(j+3);
        uint4 v0 = *(const uint4*)(yb + ((unsigned)s0*64u + offb));
        uint4 v1 = *(const uint4*)(yb + ((unsigned)s1*64u + offb));
        uint4 v2 = *(const uint4*)(yb + ((unsigned)s2*64u + offb));
        uint4 v3 = *(const uint4*)(yb + ((unsigned)s3*64u + offb));
        m0=pkmax(m0,v0.x); m1=pkmax(m1,v0.y); m2=pkmax(m2,v0.z); m3=pkmax(m3,v0.w);
        m0=pkmax(m0,v1.x); m1=pkmax(m1,v1.y); m2=pkmax(m2,v1.z); m3=pkmax(m3,v1.w);
        m0=pkmax(m0,v2.x); m1=pkmax(m1,v2.y); m2=pkmax(m2,v2.z); m3=pkmax(m3,v2.w);
        m0=pkmax(m0,v3.x); m1=pkmax(m1,v3.y); m2=pkmax(m2,v3.z); m3=pkmax(m3,v3.w);
    }
    for(; j<end; j++){
        int s0 = idx(j);
        uint4 v0 = *(const uint4*)(yb + ((unsigned)s0*64u + offb));
        m0=pkmax(m0,v0.x); m1=pkmax(m1,v0.y); m2=pkmax(m2,v0.z); m3=pkmax(m3,v0.w);
    }
    m[0]=m0; m[1]=m1; m[2]=m2; m[3]=m3;
}

static __device__ __forceinline__ void finish_selu(const unsigned m[4], float o[8]){
    float2 f0=h2_to_f2(m[0]), f1=h2_to_f2(m[1]), f2=h2_to_f2(m[2]), f3=h2_to_f2(m[3]);
    float f[8] = {f0.x,f0.y,f1.x,f1.y,f2.x,f2.y,f3.x,f3.y};
    #pragma unroll
    for(int k=0;k<8;k++){
        float v = f[k];
        if(v < -1e30f) v = 0.0f;    // empty segment (-inf) -> 0
        o[k] = selu_f(v);
    }
}

// ---------------- tail gather: 8 lanes/node over 4MB tail array (own kernel -> L2-resident) ----------------
__global__ __launch_bounds__(256) void k_tailgather(const __half* __restrict__ ytail,
        const int* __restrict__ row_beg, const int* __restrict__ row_end,
        const int* __restrict__ csr, float* __restrict__ tf){
    int gid = blockIdx.x*256 + threadIdx.x;
    int n = gid >> 3, l = gid & 7;
    if(n >= N_NODES) return;
    const char* __restrict__ yb = (const char*)ytail;
    int beg = row_beg[n], end = row_end[n];
    unsigned m0=0xFC00FC00u, m1=0xFC00FC00u;
    for(int j=beg+l; j<end; j+=8){
        int s0 = csr[j];
        uint2 v0 = *(const uint2*)(yb + (unsigned)s0*8u);
        m0=pkmax(m0,v0.x); m1=pkmax(m1,v0.y);
    }
    // reduce across the node's 8 lanes (xor 1,2,4 stays inside aligned 8-groups)
    m0 = pkmax(m0, (unsigned)__shfl_xor((int)m0, 1, 64));
    m1 = pkmax(m1, (unsigned)__shfl_xor((int)m1, 1, 64));
    m0 = pkmax(m0, (unsigned)__shfl_xor((int)m0, 2, 64));
    m1 = pkmax(m1, (unsigned)__shfl_xor((int)m1, 2, 64));
    m0 = pkmax(m0, (unsigned)__shfl_xor((int)m0, 4, 64));
    m1 = pkmax(m1, (unsigned)__shfl_xor((int)m1, 4, 64));
    if(l < 4){
        float2 f0=h2_to_f2(m0), f1=h2_to_f2(m1);
        float v = (l==0)?f0.x:(l==1)?f0.y:(l==2)?f1.x:f1.y;
        if(v < -1e30f) v = 0.f;
        tf[(size_t)n*4 + l] = selu_f(v);   // coalesced 4B/lane
    }
}

// ---------------- fused layer: main gather-max+selu (+tail feats) -> S accum -> next transform ----------------
// 64 nodes/block, FG 16B lanes per node over 64B-aligned rows. TIN: read selu'd tail feats
// from tf (computed by k_tailgather). TNEXT: output has tail rows (dims 32..35).
template<int FG,int TIN,int D_CUR,int SOFF,int D_NEXT,int TNEXT>
__global__ __launch_bounds__(64*FG) void k_fused(
        const __half* __restrict__ ymain, const float* __restrict__ tf,
        const int* __restrict__ row_beg, const int* __restrict__ row_end,
        const int* __restrict__ csr, const int* __restrict__ batch,
        const float* __restrict__ W, const float* __restrict__ bias,
        float* __restrict__ S, __half* __restrict__ youtM, __half* __restrict__ youtT){
    const int NTH = 64*FG;
    const int NF  = TIN ? 36 : 8*FG;
    const int OW  = TNEXT ? 36 : 32;   // output halfs (zero-padded cols beyond D_NEXT)
    __shared__ float feat[64][NF+1];
    __shared__ float sw[D_CUR*OW];
    __shared__ float sb[OW];
    __shared__ int sbatch[64];
    __shared__ int scsr[CSR_CAP];
    int t = threadIdx.x;
    int nl = t / FG, fg = t - nl*FG;
    int base = blockIdx.x*64;
    int n = base + nl;
    for(int i=t;i<D_CUR*OW;i+=NTH){
        int k=i/OW, o2=i-k*OW;
        sw[i] = (o2<D_NEXT) ? W[k*D_NEXT+o2] : 0.f;
    }
    if(t<OW) sb[t] = (t<D_NEXT) ? bias[t] : 0.f;
    if(t<64) sbatch[t] = (base+t<N_NODES) ? batch[base+t] : -1;
    // stage this block's csr index span into LDS (coalesced)
    int last = base + 63; if(last >= N_NODES) last = N_NODES-1;
    int ebeg = row_beg[base];
    int nst = row_end[last] - ebeg; if(nst > CSR_CAP) nst = CSR_CAP;
    for(int i=t;i<nst;i+=NTH) scsr[i] = csr[ebeg+i];
    __syncthreads();
    int slim = ebeg + nst;
    float o[8];
    if(n < N_NODES){
        int beg = row_beg[n], end = row_end[n];
        unsigned m[4] = {0xFC00FC00u,0xFC00FC00u,0xFC00FC00u,0xFC00FC00u};
        unsigned offb = (unsigned)fg*16u;
        if(end <= slim) gather_max_m(ymain, [&](int j){ return scsr[j-ebeg]; }, beg, end, offb, m);
        else            gather_max_m(ymain, [&](int j){ return csr[j]; },       beg, end, offb, m);
        finish_selu(m, o);
    } else {
        for(int k=0;k<8;k++) o[k]=0.f;
    }
    #pragma unroll
    for(int k=0;k<8;k++) feat[nl][8*fg+k] = o[k];
    if(TIN && fg == 0){
        if(n < N_NODES){
            float4 tv = ((const float4*)tf)[n];
            feat[nl][32]=tv.x; feat[nl][33]=tv.y; feat[nl][34]=tv.z; feat[nl][35]=tv.w;
        } else {
            feat[nl][32]=0.f; feat[nl][33]=0.f; feat[nl][34]=0.f; feat[nl][35]=0.f;
        }
    }
    __syncthreads();
    // per-graph run reduction into S (batch sorted)
    if(t < D_CUR){
        float acc=0.f; int gprev = sbatch[0];
        for(int mm=0;mm<64;mm++){
            int g = sbatch[mm];
            if(g<0) break;
            if(g!=gprev){ atomicAdd(&S[(size_t)gprev*SD+SOFF+t], acc); acc=0.f; gprev=g; }
            acc += feat[mm][t];
        }
        if(gprev>=0) atomicAdd(&S[(size_t)gprev*SD+SOFF+t], acc);
    }
    // next-layer transform from LDS
    if(n < N_NODES){
        for(int p=fg; p<OW/2; p+=FG){
            int c0=2*p, c1=c0+1;
            float a0=sb[c0], a1=sb[c1];
            #pragma unroll
            for(int k=0;k<D_CUR;k++){
                float fv = feat[nl][k];
                a0 = fmaf(fv, sw[k*OW+c0], a0);
                a1 = fmaf(fv, sw[k*OW+c1], a1);
            }
            __half2 hv = __floats2half2_rn(a0,a1);
            if(!TNEXT || p < 16) ((__half2*)youtM)[(size_t)n*16 + p] = hv;
            else                 ((__half2*)youtT)[(size_t)n*2 + (p-16)] = hv;
        }
    }
}

// ---------------- fused last layer: main gather (+tail feats) -> S accum only ----------------
template<int FG,int TIN,int D_CUR,int SOFF>
__global__ __launch_bounds__(64*FG) void k_fused_last(
        const __half* __restrict__ ymain, const float* __restrict__ tf,
        const int* __restrict__ row_beg, const int* __restrict__ row_end,
        const int* __restrict__ csr, const int* __restrict__ batch,
        float* __restrict__ S){
    const int NTH = 64*FG;
    const int NF  = TIN ? 36 : 8*FG;
    __shared__ float feat[64][NF+1];
    __shared__ int sbatch[64];
    __shared__ int scsr[CSR_CAP];
    int t = threadIdx.x;
    int nl = t / FG, fg = t - nl*FG;
    int base = blockIdx.x*64;
    int n = base + nl;
    if(t<64) sbatch[t] = (base+t<N_NODES) ? batch[base+t] : -1;
    int last = base + 63; if(last >= N_NODES) last = N_NODES-1;
    int ebeg = row_beg[base];
    int nst = row_end[last] - ebeg; if(nst > CSR_CAP) nst = CSR_CAP;
    for(int i=t;i<nst;i+=NTH) scsr[i] = csr[ebeg+i];
    __syncthreads();
    int slim = ebeg + nst;
    float o[8];
    if(n < N_NODES){
        int beg = row_beg[n], end = row_end[n];
        unsigned m[4] = {0xFC00FC00u,0xFC00FC00u,0xFC00FC00u,0xFC00FC00u};
        unsigned offb = (unsigned)fg*16u;
        if(end <= slim) gather_max_m(ymain, [&](int j){ return scsr[j-ebeg]; }, beg, end, offb, m);
        else            gather_max_m(ymain, [&](int j){ return csr[j]; },       beg, end, offb, m);
        finish_selu(m, o);
    } else {
        for(int k=0;k<8;k++) o[k]=0.f;
    }
    #pragma unroll
    for(int k=0;k<8;k++) feat[nl][8*fg+k] = o[k];
    if(TIN && fg == 0){
        if(n < N_NODES){
            float4 tv = ((const float4*)tf)[n];
            feat[nl][32]=tv.x; feat[nl][33]=tv.y; feat[nl][34]=tv.z; feat[nl][35]=tv.w;
        } else {
            feat[nl][32]=0.f; feat[nl][33]=0.f; feat[nl][34]=0.f; feat[nl][35]=0.f;
        }
    }
    __syncthreads();
    if(t < D_CUR){
        float acc=0.f; int gprev = sbatch[0];
        for(int mm=0;mm<64;mm++){
            int g = sbatch[mm];
            if(g<0) break;
            if(g!=gprev){ atomicAdd(&S[(size_t)gprev*SD+SOFF+t], acc); acc=0.f; gprev=g; }
            acc += feat[mm][t];
        }
        if(gprev>=0) atomicAdd(&S[(size_t)gprev*SD+SOFF+t], acc);
    }
}

// ---------------- fused readout + fc1: r = S@Wcat + b (LDS), z1 = [r,mol]@wf + bf, BN stats ----------------
__global__ __launch_bounds__(192) void k_rfc1(const float* __restrict__ S, const float* __restrict__ mol,
    const float* __restrict__ w1,const float* __restrict__ b1,
    const float* __restrict__ w2,const float* __restrict__ b2,
    const float* __restrict__ w3,const float* __restrict__ b3,
    const float* __restrict__ w4,const float* __restrict__ b4,
    const float* __restrict__ wf, const float* __restrict__ bf,
    float* __restrict__ z1, float* __restrict__ ps, float* __restrict__ pq){
    __shared__ float sH[GPB][SD];
    __shared__ float sR[GPB][RD+10];
    int t = threadIdx.x;
    int g0 = blockIdx.x*GPB;
    for(int i=t;i<GPB*SD;i+=192){
        int gl=i/SD, k=i-gl*SD;
        int g=g0+gl;
        sH[gl][k] = (g<N_GRAPHS) ? S[(size_t)g*SD+k] : 0.f;
    }
    for(int i=t;i<GPB*10;i+=192){
        int gl=i/10, k=i-gl*10;
        int g=g0+gl;
        sR[gl][RD+k] = (g<N_GRAPHS) ? mol[(size_t)g*10+k] : 0.f;
    }
    __syncthreads();
    int j = t;
    if(j < RD){
        float acc[GPB];
        float bj = b1[j]+b2[j]+b3[j]+b4[j];
        #pragma unroll
        for(int gl=0;gl<GPB;gl++) acc[gl]=bj;
        for(int k=0;k<20;k++){ float wv=w1[k*RD+j];
            #pragma unroll
            for(int gl=0;gl<GPB;gl++) acc[gl] += sH[gl][k]*wv; }
        for(int k=0;k<27;k++){ float wv=w2[k*RD+j];
            #pragma unroll
            for(int gl=0;gl<GPB;gl++) acc[gl] += sH[gl][20+k]*wv; }
        for(int k=0;k<36;k++){ float wv=w3[k*RD+j];
            #pragma unroll
            for(int gl=0;gl<GPB;gl++) acc[gl] += sH[gl][47+k]*wv; }
        for(int k=0;k<36;k++){ float wv=w4[k*RD+j];
            #pragma unroll
            for(int gl=0;gl<GPB;gl++) acc[gl] += sH[gl][83+k]*wv; }
        #pragma unroll
        for(int gl=0;gl<GPB;gl++) sR[gl][j] = acc[gl];
    }
    __syncthreads();
    if(j < H1){
        float acc[GPB]; float bj=bf[j];
        #pragma unroll
        for(int gl=0;gl<GPB;gl++) acc[gl]=bj;
        for(int k=0;k<RD+10;k++){
            float wv = wf[k*H1+j];
            #pragma unroll
            for(int gl=0;gl<GPB;gl++) acc[gl] += sR[gl][k]*wv;
        }
        int ng = min(GPB, N_GRAPHS-g0);
        float psum=0.f, psq=0.f;
        for(int gl=0;gl<ng;gl++){
            z1[(size_t)(g0+gl)*H1+j]=acc[gl];
            psum+=acc[gl]; psq+=acc[gl]*acc[gl];
        }
        ps[blockIdx.x*H1+j]=psum;
        pq[blockIdx.x*H1+j]=psq;
    }
}

// ---------------- BN finalize: a = g/sqrt(var+eps), c = b - a*mu ----------------
__global__ __launch_bounds__(256) void k_bnfin(const float* __restrict__ ps, const float* __restrict__ pq,
    int nb, int H, const float* __restrict__ gamma, const float* __restrict__ beta,
    float* __restrict__ a, float* __restrict__ c){
    int j = blockIdx.x;
    int t = threadIdx.x;
    float s=0.f, q=0.f;
    for(int i=t;i<nb;i+=256){ s+=ps[(size_t)i*H+j]; q+=pq[(size_t)i*H+j]; }
    __shared__ float sh1[256], sh2[256];
    sh1[t]=s; sh2[t]=q; __syncthreads();
    for(int off=128;off>0;off>>=1){
        if(t<off){ sh1[t]+=sh1[t+off]; sh2[t]+=sh2[t+off]; }
        __syncthreads();
    }
    if(t==0){
        float mean = sh1[0]/(float)N_GRAPHS;
        float var  = sh2[0]/(float)N_GRAPHS - mean*mean;
        float inv  = 1.0f/sqrtf(var + 1e-5f);
        float aj = gamma[j]*inv;
        a[j]=aj; c[j]=beta[j]-aj*mean;
    }
}

// ---------------- fc2: z2 = relu(bn1(z1)) @ w + b, + BN partial stats ----------------
__global__ __launch_bounds__(64) void k_fc2(const float* __restrict__ z1, const float* __restrict__ a1,
    const float* __restrict__ c1, const float* __restrict__ w, const float* __restrict__ b,
    float* __restrict__ z2, float* __restrict__ ps, float* __restrict__ pq){
    __shared__ float sH[GPB][H1];
    int t = threadIdx.x;
    int g0 = blockIdx.x*GPB;
    for(int i=t;i<GPB*H1;i+=64){
        int gl=i/H1, k=i-gl*H1;
        int g=g0+gl;
        float v=0.f;
        if(g<N_GRAPHS){ float z=z1[(size_t)g*H1+k]; v=fmaxf(a1[k]*z+c1[k],0.f); }
        sH[gl][k]=v;
    }
    __syncthreads();
    int j = t;
    if(j < H2){
        float acc[GPB]; float bj=b[j];
        #pragma unroll
        for(int gl=0;gl<GPB;gl++) acc[gl]=bj;
        for(int k=0;k<H1;k++){
            float wv=w[k*H2+j];
            #pragma unroll
            for(int gl=0;gl<GPB;gl++) acc[gl]+=sH[gl][k]*wv;
        }
        int ng=min(GPB,N_GRAPHS-g0);
        float psum=0.f,psq=0.f;
        for(int gl=0;gl<ng;gl++){
            z2[(size_t)(g0+gl)*H2+j]=acc[gl];
            psum+=acc[gl]; psq+=acc[gl]*acc[gl];
        }
        ps[blockIdx.x*H2+j]=psum; pq[blockIdx.x*H2+j]=psq;
    }
}

// ---------------- out: sigmoid(relu(bn2(z2)) @ w + b) ----------------
__global__ __launch_bounds__(192) void k_out(const float* __restrict__ z2, const float* __restrict__ a2,
    const float* __restrict__ c2, const float* __restrict__ w, const float* __restrict__ b,
    float* __restrict__ out){
    __shared__ float sH[GPB][H2];
    int t = threadIdx.x;
    int g0 = blockIdx.x*GPB;
    for(int i=t;i<GPB*H2;i+=192){
        int gl=i/H2, k=i-gl*H2;
        int g=g0+gl;
        float v=0.f;
        if(g<N_GRAPHS){ float z=z2[(size_t)g*H2+k]; v=fmaxf(a2[k]*z+c2[k],0.f); }
        sH[gl][k]=v;
    }
    __syncthreads();
    int j = t;
    if(j < NT){
        float acc[GPB]; float bj=b[j];
        #pragma unroll
        for(int gl=0;gl<GPB;gl++) acc[gl]=bj;
        for(int k=0;k<H2;k++){
            float wv=w[k*NT+j];
            #pragma unroll
            for(int gl=0;gl<GPB;gl++) acc[gl]+=sH[gl][k]*wv;
        }
        int ng=min(GPB,N_GRAPHS-g0);
        for(int gl=0;gl<ng;gl++)
            out[(size_t)(g0+gl)*NT+j] = 1.0f/(1.0f+__expf(-acc[gl]));
    }
}

// ---------------- launcher ----------------
static inline int ceil_div(int a,int b){ return (a+b-1)/b; }

extern "C" void kernel_launch(void* const* d_in, const int* in_sizes, int n_in,
                              void* d_out, int out_size, void* d_ws, size_t ws_size,
                              hipStream_t stream) {
    const float* x     = (const float*)d_in[0];
    const float* mol   = (const float*)d_in[1];
    const int*   ei    = (const int*)  d_in[2];   // [0:E]=src, [E:2E]=dst
    const int*   batch = (const int*)  d_in[3];
    const float* w_g1=(const float*)d_in[4];  const float* b_g1=(const float*)d_in[5];
    const float* w_g2=(const float*)d_in[6];  const float* b_g2=(const float*)d_in[7];
    const float* w_g3=(const float*)d_in[8];  const float* b_g3=(const float*)d_in[9];
    const float* w_g4=(const float*)d_in[10]; const float* b_g4=(const float*)d_in[11];
    const float* w_r1=(const float*)d_in[12]; const float* b_r1=(const float*)d_in[13];
    const float* w_r2=(const float*)d_in[14]; const float* b_r2=(const float*)d_in[15];
    const float* w_r3=(const float*)d_in[16]; const float* b_r3=(const float*)d_in[17];
    const float* w_r4=(const float*)d_in[18]; const float* b_r4=(const float*)d_in[19];
    const float* w_fc1=(const float*)d_in[20]; const float* b_fc1=(const float*)d_in[21];
    const float* bn1_g=(const float*)d_in[22]; const float* bn1_b=(const float*)d_in[23];
    const float* w_fc2=(const float*)d_in[24]; const float* b_fc2=(const float*)d_in[25];
    const float* bn2_g=(const float*)d_in[26]; const float* bn2_b=(const float*)d_in[27];
    const float* w_out=(const float*)d_in[28]; const float* b_out=(const float*)d_in[29];
    float* out = (float*)d_out;

    // workspace carve-up (256B aligned regions)
    char* p = (char*)d_ws;
    auto take=[&](size_t bytes)->char*{ char* q=p; p += (bytes+255)&~(size_t)255; return q; };
    __half* yAm = (__half*)take((size_t)N_NODES*64);   // main rows: 32 halfs, 64B aligned
    __half* yBm = (__half*)take((size_t)N_NODES*64);
    __half* yAt = (__half*)take((size_t)N_NODES*8);    // tail rows: 4 halfs (dims 32..35)
    __half* yBt = (__half*)take((size_t)N_NODES*8);
    float* tf   = (float*)take((size_t)N_NODES*16);    // selu'd tail feats (fp32 x4)
    int* bcur    = (int*)take((size_t)NBUCK2*4);
    int* row_beg = (int*)take((size_t)N_NODES*4);
    int* row_end = (int*)take((size_t)N_NODES*4);
    int* packed  = (int*)take((size_t)NBUCK2*REG*4);
    int* csr     = (int*)take((size_t)NBUCK2*REG*4);
    float* S  = (float*)take((size_t)N_GRAPHS*SD*4);
    float* z1 = (float*)take((size_t)N_GRAPHS*H1*4);
    float* z2 = (float*)take((size_t)N_GRAPHS*H2*4);
    const int NB_G = ceil_div(N_GRAPHS, GPB);   // 1563
    float* p1s=(float*)take((size_t)NB_G*H1*4);
    float* p1q=(float*)take((size_t)NB_G*H1*4);
    float* p2s=(float*)take((size_t)NB_G*H2*4);
    float* p2q=(float*)take((size_t)NB_G*H2*4);
    float* a1=(float*)take(H1*4); float* c1=(float*)take(H1*4);
    float* a2=(float*)take(H2*4); float* c2=(float*)take(H2*4);

    const int* src = ei;
    const int* dst = ei + N_EDGES;

    // ---- CSR build (two-pass, coalesced writes; round-7 proved random 4B scatter = 5x worse) ----
    k_init<<<ceil_div(N_GRAPHS*SD,256),256,0,stream>>>(bcur,S);
    k_bin<<<NB_BIN,256,0,stream>>>(src,dst,bcur,packed);
    k_scatfine<<<NBUCK2,1024,0,stream>>>(bcur,packed,row_beg,row_end,csr);

    // layer 1 transform: x(48 fp32) -> yAm(fp16, 64B rows, D=20 zero-pad)
    k_transform_h<48,20,48,32><<<ceil_div(N_NODES*16,256),256,0,stream>>>(x,w_g1,b_g1,yAm);
    // fused layers: 1-line main gathers; D=36 tail dims via dedicated L2-resident kernel
    k_fused<3,0,20,0, 27,0><<<NBF,192,0,stream>>>(yAm,tf,row_beg,row_end,csr,batch,w_g2,b_g2,S,yBm,yBt);
    k_fused<4,0,27,20,36,1><<<NBF,256,0,stream>>>(yBm,tf,row_beg,row_end,csr,batch,w_g3,b_g3,S,yAm,yAt);
    k_tailgather<<<ceil_div(N_NODES*8,256),256,0,stream>>>(yAt,row_beg,row_end,csr,tf);
    k_fused<4,1,36,47,36,1><<<NBF,256,0,stream>>>(yAm,tf,row_beg,row_end,csr,batch,w_g4,b_g4,S,yBm,yBt);
    k_tailgather<<<ceil_div(N_NODES*8,256),256,0,stream>>>(yBt,row_beg,row_end,csr,tf);
    k_fused_last<4,1,36,83><<<NBF,256,0,stream>>>(yBm,tf,row_beg,row_end,csr,batch,S);

    // dense tail: fused readout+fc1, BN, fc2, BN, out
    k_rfc1<<<NB_G,192,0,stream>>>(S,mol,w_r1,b_r1,w_r2,b_r2,w_r3,b_r3,w_r4,b_r4,w_fc1,b_fc1,z1,p1s,p1q);
    k_bnfin<<<H1,256,0,stream>>>(p1s,p1q,NB_G,H1,bn1_g,bn1_b,a1,c1);
    k_fc2<<<NB_G,64,0,stream>>>(z1,a1,c1,w_fc2,b_fc2,z2,p2s,p2q);
    k_bnfin<<<H2,256,0,stream>>>(p2s,p2q,NB_G,H2,bn2_g,bn2_b,a2,c2);
    k_out<<<NB_G,192,0,stream>>>(z2,a2,c2,w_out,b_out,out);
}